// Round 2
// baseline (2123.100 us; speedup 1.0000x reference)
//
#include <hip/hip_runtime.h>

#define USER_NUM 100000
#define ITEM_NUM 50000
#define FDIM 64
#define N_EDGES 1600000
#define BATCH 4096

// out[row][f] = x[row][f] * d[row]   (row-broadcast scale), float4-vectorized
__global__ void scale_rows(const float* __restrict__ x,
                           const float* __restrict__ d,
                           float* __restrict__ out, int n4) {
    int idx = blockIdx.x * blockDim.x + threadIdx.x;  // one float4 per thread
    if (idx >= n4) return;
    int row = idx >> 4;  // FDIM/4 = 16 float4 per row
    float4 v = reinterpret_cast<const float4*>(x)[idx];
    float s = d[row];
    v.x *= s; v.y *= s; v.z *= s; v.w *= s;
    reinterpret_cast<float4*>(out)[idx] = v;
}

// One 64-lane wave per edge: out[dst][lane] += val * x[src][lane]
__global__ void spmm_scatter(const float* __restrict__ x,
                             const float* __restrict__ vals,
                             const int* __restrict__ src_idx,
                             const int* __restrict__ dst_idx,
                             float* __restrict__ out,
                             int n_edges) {
    int e = blockIdx.x * (blockDim.x >> 6) + (threadIdx.x >> 6);
    if (e >= n_edges) return;
    int lane = threadIdx.x & 63;
    float v = vals[e];
    int s = src_idx[e];
    int d = dst_idx[e];
    float xv = x[s * FDIM + lane];
    atomicAdd(&out[d * FDIM + lane], v * xv);
}

// One wave per batch element: dot products over 4 layers (256 dims total)
__global__ void batch_pred(const float* __restrict__ u0, const float* __restrict__ u1,
                           const float* __restrict__ u2, const float* __restrict__ u3,
                           const float* __restrict__ i0, const float* __restrict__ i1,
                           const float* __restrict__ i2, const float* __restrict__ i3,
                           const int* __restrict__ user, const int* __restrict__ item_i,
                           const int* __restrict__ item_j,
                           float* __restrict__ pred_i, float* __restrict__ pred_j,
                           float* __restrict__ l2_terms, float* __restrict__ lsg_terms) {
    int b = blockIdx.x * (blockDim.x >> 6) + (threadIdx.x >> 6);
    if (b >= BATCH) return;
    int lane = threadIdx.x & 63;
    int uu = user[b], ii = item_i[b], ij = item_j[b];
    const float* U[4] = {u0, u1, u2, u3};
    const float* I[4] = {i0, i1, i2, i3};
    float pi = 0.f, pj = 0.f, l2 = 0.f;
#pragma unroll
    for (int k = 0; k < 4; ++k) {
        float ue = U[k][uu * FDIM + lane];
        float vi = I[k][ii * FDIM + lane];
        float vj = I[k][ij * FDIM + lane];
        pi += ue * vi;
        pj += ue * vj;
        l2 += ue * ue + vi * vi + vj * vj;
    }
#pragma unroll
    for (int m = 32; m >= 1; m >>= 1) {
        pi += __shfl_xor(pi, m, 64);
        pj += __shfl_xor(pj, m, 64);
        l2 += __shfl_xor(l2, m, 64);
    }
    if (lane == 0) {
        pred_i[b] = pi;
        pred_j[b] = pj;
        l2_terms[b] = 0.01f * l2;
        float x = pi - pj;
        // log_sigmoid(x), numerically stable
        lsg_terms[b] = fminf(x, 0.f) - log1pf(expf(-fabsf(x)));
    }
}

__global__ void final_reduce(const float* __restrict__ l2_terms,
                             const float* __restrict__ lsg_terms,
                             float* __restrict__ out_loss,
                             float* __restrict__ out_loss2) {
    __shared__ float s1[256];
    __shared__ float s2[256];
    int t = threadIdx.x;
    float a = 0.f, b = 0.f;
    for (int i = t; i < BATCH; i += 256) {
        a += l2_terms[i];
        b += lsg_terms[i];
    }
    s1[t] = a; s2[t] = b;
    __syncthreads();
    for (int s = 128; s >= 1; s >>= 1) {
        if (t < s) { s1[t] += s1[t + s]; s2[t] += s2[t + s]; }
        __syncthreads();
    }
    if (t == 0) {
        float loss2 = -s2[0] / (float)BATCH;
        float loss = loss2 + s1[0] / (float)BATCH;
        *out_loss = loss;
        *out_loss2 = loss2;
    }
}

extern "C" void kernel_launch(void* const* d_in, const int* in_sizes, int n_in,
                              void* d_out, int out_size, void* d_ws, size_t ws_size,
                              hipStream_t stream) {
    const float* eu      = (const float*)d_in[0];  // [USER_NUM, 64]
    const float* ei      = (const float*)d_in[1];  // [ITEM_NUM, 64]
    const float* d_i     = (const float*)d_in[2];  // [USER_NUM, 1]
    const float* d_j     = (const float*)d_in[3];  // [ITEM_NUM, 1]
    const float* vals    = (const float*)d_in[4];  // [N_EDGES]
    const int*   e_users = (const int*)d_in[5];
    const int*   e_items = (const int*)d_in[6];
    const int*   user    = (const int*)d_in[7];
    const int*   item_i  = (const int*)d_in[8];
    const int*   item_j  = (const int*)d_in[9];

    float* ws = (float*)d_ws;
    float* u1 = ws;
    float* u2 = u1 + (size_t)USER_NUM * FDIM;
    float* u3 = u2 + (size_t)USER_NUM * FDIM;
    float* i1 = u3 + (size_t)USER_NUM * FDIM;
    float* i2 = i1 + (size_t)ITEM_NUM * FDIM;
    float* i3 = i2 + (size_t)ITEM_NUM * FDIM;
    float* l2t  = i3 + (size_t)ITEM_NUM * FDIM;
    float* lsgt = l2t + BATCH;

    float* outp   = (float*)d_out;
    float* pred_i = outp;
    float* pred_j = outp + BATCH;
    float* loss   = outp + 2 * BATCH;
    float* loss2  = loss + 1;

    dim3 blk(256);
    int nU4 = USER_NUM * (FDIM / 4);
    int nI4 = ITEM_NUM * (FDIM / 4);
    int gridU = (nU4 + 255) / 256;
    int gridI = (nI4 + 255) / 256;
    int egrid = (N_EDGES + 3) / 4;  // 4 edges (waves) per 256-thread block

    const float* ucur = eu;
    const float* icur = ei;
    float* uout[3] = {u1, u2, u3};
    float* iout[3] = {i1, i2, i3};
    for (int k = 0; k < 3; ++k) {
        // u_k = ui_mm(i_{k-1}) + u_{k-1} * d_i
        scale_rows<<<gridU, blk, 0, stream>>>(ucur, d_i, uout[k], nU4);
        // i_k = iu_mm(u_{k-1}) + i_{k-1} * d_j
        scale_rows<<<gridI, blk, 0, stream>>>(icur, d_j, iout[k], nI4);
        spmm_scatter<<<egrid, blk, 0, stream>>>(icur, vals, e_items, e_users, uout[k], N_EDGES);
        spmm_scatter<<<egrid, blk, 0, stream>>>(ucur, vals, e_users, e_items, iout[k], N_EDGES);
        ucur = uout[k];
        icur = iout[k];
    }

    batch_pred<<<(BATCH + 3) / 4, blk, 0, stream>>>(
        eu, u1, u2, u3, ei, i1, i2, i3,
        user, item_i, item_j, pred_i, pred_j, l2t, lsgt);
    final_reduce<<<1, 256, 0, stream>>>(l2t, lsgt, loss, loss2);
}

// Round 3
// 1122.173 us; speedup vs baseline: 1.8920x; 1.8920x over previous
//
#include <hip/hip_runtime.h>

#define USER_NUM 100000
#define ITEM_NUM 50000
#define FDIM 64
#define N_EDGES 1600000
#define BATCH 4096

// ---------------- CSR build ----------------

__global__ void zero_ints(int* __restrict__ a, int n) {
    int i = blockIdx.x * blockDim.x + threadIdx.x;
    if (i < n) a[i] = 0;
}

__global__ void hist_kernel(const int* __restrict__ eu, const int* __restrict__ ei,
                            int* __restrict__ cntU, int* __restrict__ cntI, int n) {
    int e = blockIdx.x * blockDim.x + threadIdx.x;
    if (e >= n) return;
    atomicAdd(&cntU[eu[e]], 1);
    atomicAdd(&cntI[ei[e]], 1);
}

// single-block exclusive scan: row_ptr[0..n] from cnt[0..n-1]
__global__ void exclusive_scan(const int* __restrict__ cnt, int* __restrict__ row_ptr, int n) {
    __shared__ int partial[1024];
    int t = threadIdx.x;
    int per = (n + 1023) / 1024;
    int start = t * per;
    int end = min(start + per, n);
    if (start > n) start = n;
    int sum = 0;
    for (int i = start; i < end; ++i) sum += cnt[i];
    partial[t] = sum;
    __syncthreads();
    for (int off = 1; off < 1024; off <<= 1) {
        int v = (t >= off) ? partial[t - off] : 0;
        __syncthreads();
        partial[t] += v;
        __syncthreads();
    }
    int base = (t == 0) ? 0 : partial[t - 1];
    int run = base;
    for (int i = start; i < end; ++i) { row_ptr[i] = run; run += cnt[i]; }
    if (end == n) row_ptr[n] = run;  // all threads hitting tail write same total
}

// scatter edges into both CSRs as packed (col, val_bits) int2
__global__ void scatter_kernel(const int* __restrict__ eu, const int* __restrict__ ei,
                               const float* __restrict__ vals,
                               const int* __restrict__ rpU, const int* __restrict__ rpI,
                               int* __restrict__ curU, int* __restrict__ curI,
                               int2* __restrict__ edU, int2* __restrict__ edI, int n) {
    int e = blockIdx.x * blockDim.x + threadIdx.x;
    if (e >= n) return;
    int u = eu[e], it = ei[e];
    int vb = __float_as_int(vals[e]);
    int pu = rpU[u] + atomicAdd(&curU[u], 1);
    edU[pu] = make_int2(it, vb);
    int pi = rpI[it] + atomicAdd(&curI[it], 1);
    edI[pi] = make_int2(u, vb);
}

// ---------------- gather SpMM (fused self-scale) ----------------
// out[r][lane] = dscale[r]*xself[r][lane] + sum_e val_e * xsrc[col_e][lane]
__global__ void spmm_gather(const float* __restrict__ xsrc, const float* __restrict__ xself,
                            const float* __restrict__ dscale,
                            const int2* __restrict__ edges, const int* __restrict__ rp,
                            float* __restrict__ out, int nrows) {
    int r = blockIdx.x * (blockDim.x >> 6) + (threadIdx.x >> 6);
    if (r >= nrows) return;
    int lane = threadIdx.x & 63;
    float acc = dscale[r] * xself[(size_t)r * FDIM + lane];
    int b = rp[r], e2 = rp[r + 1];
    int e = b;
    // 2-edge unrolled with independent gathers to hide latency
    for (; e + 1 < e2; e += 2) {
        int2 ed0 = edges[e];
        int2 ed1 = edges[e + 1];
        float x0 = xsrc[(size_t)ed0.x * FDIM + lane];
        float x1 = xsrc[(size_t)ed1.x * FDIM + lane];
        acc = fmaf(__int_as_float(ed0.y), x0, acc);
        acc = fmaf(__int_as_float(ed1.y), x1, acc);
    }
    if (e < e2) {
        int2 ed0 = edges[e];
        acc = fmaf(__int_as_float(ed0.y), xsrc[(size_t)ed0.x * FDIM + lane], acc);
    }
    out[(size_t)r * FDIM + lane] = acc;
}

// ---------------- fallback (round-2 proven) ----------------

__global__ void scale_rows(const float* __restrict__ x, const float* __restrict__ d,
                           float* __restrict__ out, int n4) {
    int idx = blockIdx.x * blockDim.x + threadIdx.x;
    if (idx >= n4) return;
    int row = idx >> 4;
    float4 v = reinterpret_cast<const float4*>(x)[idx];
    float s = d[row];
    v.x *= s; v.y *= s; v.z *= s; v.w *= s;
    reinterpret_cast<float4*>(out)[idx] = v;
}

__global__ void spmm_scatter(const float* __restrict__ x, const float* __restrict__ vals,
                             const int* __restrict__ src_idx, const int* __restrict__ dst_idx,
                             float* __restrict__ out, int n_edges) {
    int e = blockIdx.x * (blockDim.x >> 6) + (threadIdx.x >> 6);
    if (e >= n_edges) return;
    int lane = threadIdx.x & 63;
    float v = vals[e];
    int s = src_idx[e];
    int d = dst_idx[e];
    atomicAdd(&out[d * FDIM + lane], v * x[s * FDIM + lane]);
}

// ---------------- scoring head ----------------

__global__ void batch_pred(const float* __restrict__ u0, const float* __restrict__ u1,
                           const float* __restrict__ u2, const float* __restrict__ u3,
                           const float* __restrict__ i0, const float* __restrict__ i1,
                           const float* __restrict__ i2, const float* __restrict__ i3,
                           const int* __restrict__ user, const int* __restrict__ item_i,
                           const int* __restrict__ item_j,
                           float* __restrict__ pred_i, float* __restrict__ pred_j,
                           float* __restrict__ l2_terms, float* __restrict__ lsg_terms) {
    int b = blockIdx.x * (blockDim.x >> 6) + (threadIdx.x >> 6);
    if (b >= BATCH) return;
    int lane = threadIdx.x & 63;
    int uu = user[b], ii = item_i[b], ij = item_j[b];
    const float* U[4] = {u0, u1, u2, u3};
    const float* I[4] = {i0, i1, i2, i3};
    float pi = 0.f, pj = 0.f, l2 = 0.f;
#pragma unroll
    for (int k = 0; k < 4; ++k) {
        float ue = U[k][(size_t)uu * FDIM + lane];
        float vi = I[k][(size_t)ii * FDIM + lane];
        float vj = I[k][(size_t)ij * FDIM + lane];
        pi += ue * vi;
        pj += ue * vj;
        l2 += ue * ue + vi * vi + vj * vj;
    }
#pragma unroll
    for (int m = 32; m >= 1; m >>= 1) {
        pi += __shfl_xor(pi, m, 64);
        pj += __shfl_xor(pj, m, 64);
        l2 += __shfl_xor(l2, m, 64);
    }
    if (lane == 0) {
        pred_i[b] = pi;
        pred_j[b] = pj;
        l2_terms[b] = 0.01f * l2;
        float x = pi - pj;
        lsg_terms[b] = fminf(x, 0.f) - log1pf(expf(-fabsf(x)));
    }
}

__global__ void final_reduce(const float* __restrict__ l2_terms,
                             const float* __restrict__ lsg_terms,
                             float* __restrict__ out_loss, float* __restrict__ out_loss2) {
    __shared__ float s1[256];
    __shared__ float s2[256];
    int t = threadIdx.x;
    float a = 0.f, b = 0.f;
    for (int i = t; i < BATCH; i += 256) { a += l2_terms[i]; b += lsg_terms[i]; }
    s1[t] = a; s2[t] = b;
    __syncthreads();
    for (int s = 128; s >= 1; s >>= 1) {
        if (t < s) { s1[t] += s1[t + s]; s2[t] += s2[t + s]; }
        __syncthreads();
    }
    if (t == 0) {
        float loss2 = -s2[0] / (float)BATCH;
        *out_loss = loss2 + s1[0] / (float)BATCH;
        *out_loss2 = loss2;
    }
}

extern "C" void kernel_launch(void* const* d_in, const int* in_sizes, int n_in,
                              void* d_out, int out_size, void* d_ws, size_t ws_size,
                              hipStream_t stream) {
    const float* eu      = (const float*)d_in[0];
    const float* ei      = (const float*)d_in[1];
    const float* d_i     = (const float*)d_in[2];
    const float* d_j     = (const float*)d_in[3];
    const float* vals    = (const float*)d_in[4];
    const int*   e_users = (const int*)d_in[5];
    const int*   e_items = (const int*)d_in[6];
    const int*   user    = (const int*)d_in[7];
    const int*   item_i  = (const int*)d_in[8];
    const int*   item_j  = (const int*)d_in[9];

    // ---- workspace layout (word offsets; Edge arrays 8B-aligned) ----
    float* ws = (float*)d_ws;
    size_t off = 0;
    float* u1 = ws + off; off += (size_t)USER_NUM * FDIM;
    float* u2 = ws + off; off += (size_t)USER_NUM * FDIM;
    float* u3 = ws + off; off += (size_t)USER_NUM * FDIM;
    float* i1 = ws + off; off += (size_t)ITEM_NUM * FDIM;
    float* i2 = ws + off; off += (size_t)ITEM_NUM * FDIM;
    float* i3 = ws + off; off += (size_t)ITEM_NUM * FDIM;
    float* l2t  = ws + off; off += BATCH;
    float* lsgt = ws + off; off += BATCH;
    int* curU = (int*)(ws + off); off += USER_NUM;          // cursors (double as histogram)
    int* curI = (int*)(ws + off); off += ITEM_NUM;
    int* rpU  = (int*)(ws + off); off += USER_NUM + 2;      // padded even
    int* rpI  = (int*)(ws + off); off += ITEM_NUM + 2;
    int2* edU = (int2*)(ws + off); off += (size_t)2 * N_EDGES;
    int2* edI = (int2*)(ws + off); off += (size_t)2 * N_EDGES;
    size_t need_bytes = off * 4;

    float* outp   = (float*)d_out;
    float* pred_i = outp;
    float* pred_j = outp + BATCH;
    float* loss   = outp + 2 * BATCH;
    float* loss2  = loss + 1;

    dim3 blk(256);
    float* uout[3] = {u1, u2, u3};
    float* iout[3] = {i1, i2, i3};

    if (ws_size >= need_bytes) {
        // ---- CSR build ----
        int ncnt = USER_NUM + ITEM_NUM;  // curU,curI are contiguous
        zero_ints<<<(ncnt + 255) / 256, blk, 0, stream>>>(curU, ncnt);
        hist_kernel<<<(N_EDGES + 255) / 256, blk, 0, stream>>>(e_users, e_items, curU, curI, N_EDGES);
        exclusive_scan<<<1, 1024, 0, stream>>>(curU, rpU, USER_NUM);
        exclusive_scan<<<1, 1024, 0, stream>>>(curI, rpI, ITEM_NUM);
        zero_ints<<<(ncnt + 255) / 256, blk, 0, stream>>>(curU, ncnt);
        scatter_kernel<<<(N_EDGES + 255) / 256, blk, 0, stream>>>(
            e_users, e_items, vals, rpU, rpI, curU, curI, edU, edI, N_EDGES);

        // ---- 3 propagation layers, gather-based ----
        const float* ucur = eu;
        const float* icur = ei;
        int gridU = (USER_NUM + 3) / 4;  // 4 waves (rows) per 256-thread block
        int gridI = (ITEM_NUM + 3) / 4;
        for (int k = 0; k < 3; ++k) {
            spmm_gather<<<gridU, blk, 0, stream>>>(icur, ucur, d_i, edU, rpU, uout[k], USER_NUM);
            spmm_gather<<<gridI, blk, 0, stream>>>(ucur, icur, d_j, edI, rpI, iout[k], ITEM_NUM);
            ucur = uout[k];
            icur = iout[k];
        }
    } else {
        // ---- fallback: proven atomic-scatter path ----
        int nU4 = USER_NUM * (FDIM / 4);
        int nI4 = ITEM_NUM * (FDIM / 4);
        int gridU = (nU4 + 255) / 256;
        int gridI = (nI4 + 255) / 256;
        int egrid = (N_EDGES + 3) / 4;
        const float* ucur = eu;
        const float* icur = ei;
        for (int k = 0; k < 3; ++k) {
            scale_rows<<<gridU, blk, 0, stream>>>(ucur, d_i, uout[k], nU4);
            scale_rows<<<gridI, blk, 0, stream>>>(icur, d_j, iout[k], nI4);
            spmm_scatter<<<egrid, blk, 0, stream>>>(icur, vals, e_items, e_users, uout[k], N_EDGES);
            spmm_scatter<<<egrid, blk, 0, stream>>>(ucur, vals, e_users, e_items, iout[k], N_EDGES);
            ucur = uout[k];
            icur = iout[k];
        }
    }

    batch_pred<<<(BATCH + 3) / 4, blk, 0, stream>>>(
        eu, u1, u2, u3, ei, i1, i2, i3,
        user, item_i, item_j, pred_i, pred_j, l2t, lsgt);
    final_reduce<<<1, 256, 0, stream>>>(l2t, lsgt, loss, loss2);
}

// Round 4
// 741.332 us; speedup vs baseline: 2.8639x; 1.5137x over previous
//
#include <hip/hip_runtime.h>

#define USER_NUM 100000
#define ITEM_NUM 50000
#define FDIM 64
#define N_EDGES 1600000
#define BATCH 4096
#define N_CNT (USER_NUM + ITEM_NUM)
#define CHUNK 1024
#define NCHUNK ((N_CNT + CHUNK - 1) / CHUNK)   // 147

__device__ __forceinline__ unsigned short f2bf(float f) {
    unsigned u = __float_as_uint(f);
    unsigned r = (u + 0x7FFFu + ((u >> 16) & 1u)) >> 16;  // RNE
    return (unsigned short)r;
}
__device__ __forceinline__ float bf2f(unsigned short h) {
    return __uint_as_float(((unsigned)h) << 16);
}

__global__ void zero_ints(int* __restrict__ a, int n) {
    int i = blockIdx.x * blockDim.x + threadIdx.x;
    if (i < n) a[i] = 0;
}

__global__ void f32_to_bf16_k(const float* __restrict__ x, unsigned short* __restrict__ y, int n4) {
    int i = blockIdx.x * blockDim.x + threadIdx.x;
    if (i >= n4) return;
    float4 v = reinterpret_cast<const float4*>(x)[i];
    reinterpret_cast<ushort4*>(y)[i] =
        make_ushort4(f2bf(v.x), f2bf(v.y), f2bf(v.z), f2bf(v.w));
}

// histogram over concatenated [users | items] counter array
__global__ void hist_kernel(const int* __restrict__ eu, const int* __restrict__ ei,
                            int* __restrict__ cnt, int n) {
    int e = blockIdx.x * blockDim.x + threadIdx.x;
    if (e >= n) return;
    atomicAdd(&cnt[eu[e]], 1);
    atomicAdd(&cnt[USER_NUM + ei[e]], 1);
}

// ---- 3-kernel parallel exclusive scan over cnt[N_CNT] -> rp[N_CNT+1] ----
__global__ void scan_chunks(const int* __restrict__ cnt, int* __restrict__ rp,
                            int* __restrict__ part) {
    __shared__ int sh[256];
    int b = blockIdx.x, t = threadIdx.x;
    int base = b * CHUNK + t * 4;
    int v0 = 0, v1 = 0, v2 = 0, v3 = 0;
    if (base < N_CNT) {  // N_CNT % 4 == 0, so full int4 is safe
        int4 c = *reinterpret_cast<const int4*>(cnt + base);
        v0 = c.x; v1 = c.y; v2 = c.z; v3 = c.w;
    }
    int tsum = v0 + v1 + v2 + v3;
    sh[t] = tsum;
    __syncthreads();
    for (int off = 1; off < 256; off <<= 1) {
        int x = (t >= off) ? sh[t - off] : 0;
        __syncthreads();
        sh[t] += x;
        __syncthreads();
    }
    int tb = (t == 0) ? 0 : sh[t - 1];
    if (base < N_CNT) {
        int4 o;
        o.x = tb; o.y = tb + v0; o.z = tb + v0 + v1; o.w = tb + v0 + v1 + v2;
        *reinterpret_cast<int4*>(rp + base) = o;
    }
    if (t == 255) part[b] = sh[255];
}

__global__ void scan_part(int* __restrict__ part, int* __restrict__ rp) {
    __shared__ int sh[256];
    int t = threadIdx.x;
    int v = (t < NCHUNK) ? part[t] : 0;
    sh[t] = v;
    __syncthreads();
    for (int off = 1; off < 256; off <<= 1) {
        int x = (t >= off) ? sh[t - off] : 0;
        __syncthreads();
        sh[t] += x;
        __syncthreads();
    }
    if (t < NCHUNK) part[t] = (t == 0) ? 0 : sh[t - 1];
    if (t == 0) rp[N_CNT] = sh[255];  // grand total = 2*N_EDGES
}

__global__ void add_offsets(int* __restrict__ rp, const int* __restrict__ part) {
    int b = blockIdx.x, t = threadIdx.x;
    int base = b * CHUNK + t * 4;
    if (base >= N_CNT) return;
    int o = part[b];
    int4 v = *reinterpret_cast<int4*>(rp + base);
    v.x += o; v.y += o; v.z += o; v.w += o;
    *reinterpret_cast<int4*>(rp + base) = v;
}

// scatter edges into unified CSR as packed (col, val_bits)
__global__ void scatter_kernel(const int* __restrict__ eu, const int* __restrict__ ei,
                               const float* __restrict__ vals,
                               const int* __restrict__ rp, int* __restrict__ cur,
                               int2* __restrict__ edges, int n) {
    int e = blockIdx.x * blockDim.x + threadIdx.x;
    if (e >= n) return;
    int u = eu[e], it = ei[e];
    int vb = __float_as_int(vals[e]);
    int pu = rp[u] + atomicAdd(&cur[u], 1);
    edges[pu] = make_int2(it, vb);
    int ii = USER_NUM + it;
    int pi = rp[ii] + atomicAdd(&cur[ii], 1);
    edges[pi] = make_int2(u, vb);
}

// out[r][lane] = dscale[r]*xself[r][lane] + sum_e val_e * xsrc[col_e][lane]
// bf16 tables, f32 accumulate, bf16 out. One 64-lane wave per row.
__global__ void spmm_gather(const unsigned short* __restrict__ xsrc,
                            const unsigned short* __restrict__ xself,
                            const float* __restrict__ dscale,
                            const int2* __restrict__ edges,
                            const int* __restrict__ rp, int rp_off,
                            unsigned short* __restrict__ out, int nrows) {
    int r = blockIdx.x * (blockDim.x >> 6) + (threadIdx.x >> 6);
    if (r >= nrows) return;
    int lane = threadIdx.x & 63;
    float acc = dscale[r] * bf2f(xself[(size_t)r * FDIM + lane]);
    int e = rp[rp_off + r], e2 = rp[rp_off + r + 1];
    for (; e + 3 < e2; e += 4) {
        int2 a = edges[e], b = edges[e + 1], c = edges[e + 2], d = edges[e + 3];
        float x0 = bf2f(xsrc[(size_t)a.x * FDIM + lane]);
        float x1 = bf2f(xsrc[(size_t)b.x * FDIM + lane]);
        float x2 = bf2f(xsrc[(size_t)c.x * FDIM + lane]);
        float x3 = bf2f(xsrc[(size_t)d.x * FDIM + lane]);
        acc = fmaf(__int_as_float(a.y), x0, acc);
        acc = fmaf(__int_as_float(b.y), x1, acc);
        acc = fmaf(__int_as_float(c.y), x2, acc);
        acc = fmaf(__int_as_float(d.y), x3, acc);
    }
    for (; e < e2; ++e) {
        int2 a = edges[e];
        acc = fmaf(__int_as_float(a.y), bf2f(xsrc[(size_t)a.x * FDIM + lane]), acc);
    }
    out[(size_t)r * FDIM + lane] = f2bf(acc);
}

__global__ void batch_pred(const unsigned short* __restrict__ u0, const unsigned short* __restrict__ u1,
                           const unsigned short* __restrict__ u2, const unsigned short* __restrict__ u3,
                           const unsigned short* __restrict__ i0, const unsigned short* __restrict__ i1,
                           const unsigned short* __restrict__ i2, const unsigned short* __restrict__ i3,
                           const int* __restrict__ user, const int* __restrict__ item_i,
                           const int* __restrict__ item_j,
                           float* __restrict__ pred_i, float* __restrict__ pred_j,
                           float* __restrict__ l2_terms, float* __restrict__ lsg_terms) {
    int b = blockIdx.x * (blockDim.x >> 6) + (threadIdx.x >> 6);
    if (b >= BATCH) return;
    int lane = threadIdx.x & 63;
    int uu = user[b], ii = item_i[b], ij = item_j[b];
    const unsigned short* U[4] = {u0, u1, u2, u3};
    const unsigned short* I[4] = {i0, i1, i2, i3};
    float pi = 0.f, pj = 0.f, l2 = 0.f;
#pragma unroll
    for (int k = 0; k < 4; ++k) {
        float ue = bf2f(U[k][(size_t)uu * FDIM + lane]);
        float vi = bf2f(I[k][(size_t)ii * FDIM + lane]);
        float vj = bf2f(I[k][(size_t)ij * FDIM + lane]);
        pi += ue * vi;
        pj += ue * vj;
        l2 += ue * ue + vi * vi + vj * vj;
    }
#pragma unroll
    for (int m = 32; m >= 1; m >>= 1) {
        pi += __shfl_xor(pi, m, 64);
        pj += __shfl_xor(pj, m, 64);
        l2 += __shfl_xor(l2, m, 64);
    }
    if (lane == 0) {
        pred_i[b] = pi;
        pred_j[b] = pj;
        l2_terms[b] = 0.01f * l2;
        float x = pi - pj;
        lsg_terms[b] = fminf(x, 0.f) - log1pf(expf(-fabsf(x)));
    }
}

__global__ void final_reduce(const float* __restrict__ l2_terms,
                             const float* __restrict__ lsg_terms,
                             float* __restrict__ out_loss, float* __restrict__ out_loss2) {
    __shared__ float s1[256];
    __shared__ float s2[256];
    int t = threadIdx.x;
    float a = 0.f, b = 0.f;
    for (int i = t; i < BATCH; i += 256) { a += l2_terms[i]; b += lsg_terms[i]; }
    s1[t] = a; s2[t] = b;
    __syncthreads();
    for (int s = 128; s >= 1; s >>= 1) {
        if (t < s) { s1[t] += s1[t + s]; s2[t] += s2[t + s]; }
        __syncthreads();
    }
    if (t == 0) {
        float loss2 = -s2[0] / (float)BATCH;
        *out_loss = loss2 + s1[0] / (float)BATCH;
        *out_loss2 = loss2;
    }
}

extern "C" void kernel_launch(void* const* d_in, const int* in_sizes, int n_in,
                              void* d_out, int out_size, void* d_ws, size_t ws_size,
                              hipStream_t stream) {
    const float* eu      = (const float*)d_in[0];
    const float* ei      = (const float*)d_in[1];
    const float* d_i     = (const float*)d_in[2];
    const float* d_j     = (const float*)d_in[3];
    const float* vals    = (const float*)d_in[4];
    const int*   e_users = (const int*)d_in[5];
    const int*   e_items = (const int*)d_in[6];
    const int*   user    = (const int*)d_in[7];
    const int*   item_i  = (const int*)d_in[8];
    const int*   item_j  = (const int*)d_in[9];

    // ---- workspace layout (4-byte word offsets, all multiples of 4 words) ----
    float* ws = (float*)d_ws;
    size_t off = 0;
    const size_t UW = (size_t)USER_NUM * FDIM / 2;  // bf16 table in words
    const size_t IW = (size_t)ITEM_NUM * FDIM / 2;
    unsigned short* ub[4];
    unsigned short* ib[4];
    for (int k = 0; k < 4; ++k) { ub[k] = (unsigned short*)(ws + off); off += UW; }
    for (int k = 0; k < 4; ++k) { ib[k] = (unsigned short*)(ws + off); off += IW; }
    float* l2t  = ws + off; off += BATCH;
    float* lsgt = ws + off; off += BATCH;
    int* cnt  = (int*)(ws + off); off += N_CNT;        // doubles as scatter cursors
    int* rp   = (int*)(ws + off); off += N_CNT + 4;    // rp[N_CNT+1], padded
    int* part = (int*)(ws + off); off += 256;
    int2* edges = (int2*)(ws + off); off += (size_t)4 * N_EDGES;  // 2*N_EDGES int2

    float* outp   = (float*)d_out;
    float* pred_i = outp;
    float* pred_j = outp + BATCH;
    float* loss   = outp + 2 * BATCH;
    float* loss2  = loss + 1;

    dim3 blk(256);

    // ---- bf16 copies of layer-0 tables ----
    int nU4 = USER_NUM * FDIM / 4, nI4 = ITEM_NUM * FDIM / 4;
    f32_to_bf16_k<<<(nU4 + 255) / 256, blk, 0, stream>>>(eu, ub[0], nU4);
    f32_to_bf16_k<<<(nI4 + 255) / 256, blk, 0, stream>>>(ei, ib[0], nI4);

    // ---- CSR build (unified users|items) ----
    zero_ints<<<(N_CNT + 255) / 256, blk, 0, stream>>>(cnt, N_CNT);
    hist_kernel<<<(N_EDGES + 255) / 256, blk, 0, stream>>>(e_users, e_items, cnt, N_EDGES);
    scan_chunks<<<NCHUNK, blk, 0, stream>>>(cnt, rp, part);
    scan_part<<<1, blk, 0, stream>>>(part, rp);
    add_offsets<<<NCHUNK, blk, 0, stream>>>(rp, part);
    zero_ints<<<(N_CNT + 255) / 256, blk, 0, stream>>>(cnt, N_CNT);
    scatter_kernel<<<(N_EDGES + 255) / 256, blk, 0, stream>>>(
        e_users, e_items, vals, rp, cnt, edges, N_EDGES);

    // ---- 3 propagation layers (gather, fused self-scale) ----
    int gridU = (USER_NUM + 3) / 4;
    int gridI = (ITEM_NUM + 3) / 4;
    for (int k = 0; k < 3; ++k) {
        spmm_gather<<<gridU, blk, 0, stream>>>(ib[k], ub[k], d_i, edges, rp, 0, ub[k + 1], USER_NUM);
        spmm_gather<<<gridI, blk, 0, stream>>>(ub[k], ib[k], d_j, edges, rp, USER_NUM, ib[k + 1], ITEM_NUM);
    }

    batch_pred<<<(BATCH + 3) / 4, blk, 0, stream>>>(
        ub[0], ub[1], ub[2], ub[3], ib[0], ib[1], ib[2], ib[3],
        user, item_i, item_j, pred_i, pred_j, l2t, lsgt);
    final_reduce<<<1, 256, 0, stream>>>(l2t, lsgt, loss, loss2);
}

// Round 5
// 504.290 us; speedup vs baseline: 4.2101x; 1.4701x over previous
//
#include <hip/hip_runtime.h>

#define USER_NUM 100000
#define ITEM_NUM 50000
#define FDIM 64
#define N_EDGES 1600000
#define BATCH 4096
#define ROWS_TOTAL (USER_NUM + ITEM_NUM)   // 150000 unified rows (users then items)
#define BROWS 512                           // rows per bucket
#define NB ((ROWS_TOTAL + BROWS - 1) / BROWS)  // 293 buckets
#define CHUNK_E 2048                        // edges per passA workgroup
#define ENT_PER_WG (2 * CHUNK_E)            // 4096 entries

__device__ __forceinline__ unsigned short f2bf(float f) {
    unsigned u = __float_as_uint(f);
    unsigned r = (u + 0x7FFFu + ((u >> 16) & 1u)) >> 16;  // RNE
    return (unsigned short)r;
}
__device__ __forceinline__ float bf2f(unsigned short h) {
    return __uint_as_float(((unsigned)h) << 16);
}

__global__ void zero_ints(int* __restrict__ a, int n) {
    int i = blockIdx.x * blockDim.x + threadIdx.x;
    if (i < n) a[i] = 0;
}

__global__ void f32_to_bf16_k(const float* __restrict__ x, unsigned short* __restrict__ y, int n4) {
    int i = blockIdx.x * blockDim.x + threadIdx.x;
    if (i >= n4) return;
    float4 v = reinterpret_cast<const float4*>(x)[i];
    reinterpret_cast<ushort4*>(y)[i] =
        make_ushort4(f2bf(v.x), f2bf(v.y), f2bf(v.z), f2bf(v.w));
}

// LDS-aggregated bucket histogram (293 coarse buckets over unified rows)
__global__ void bucket_hist(const int* __restrict__ eu, const int* __restrict__ ei,
                            int* __restrict__ bcnt, int n) {
    __shared__ int h[NB];
    int t = threadIdx.x;
    for (int i = t; i < NB; i += 256) h[i] = 0;
    __syncthreads();
    for (int e = blockIdx.x * blockDim.x + t; e < n; e += gridDim.x * blockDim.x) {
        atomicAdd(&h[eu[e] >> 9], 1);
        atomicAdd(&h[(ei[e] + USER_NUM) >> 9], 1);
    }
    __syncthreads();
    for (int i = t; i < NB; i += 256)
        if (h[i]) atomicAdd(&bcnt[i], h[i]);
}

// single-block scan of bcnt[NB] -> brp[NB+1]; init bucket_cur; rp[ROWS_TOTAL]=total
__global__ void bucket_scan(const int* __restrict__ bcnt, int* __restrict__ brp,
                            int* __restrict__ bucket_cur, int* __restrict__ rp) {
    __shared__ int sh[512];
    int t = threadIdx.x;
    int v = (t < NB) ? bcnt[t] : 0;
    sh[t] = v;
    __syncthreads();
    for (int off = 1; off < 512; off <<= 1) {
        int x = (t >= off) ? sh[t - off] : 0;
        __syncthreads();
        sh[t] += x;
        __syncthreads();
    }
    int ex = (t == 0) ? 0 : sh[t - 1];
    if (t < NB) { brp[t] = ex; bucket_cur[t] = ex; }
    if (t == NB) brp[NB] = ex;                  // = total (v=0 for t==NB)
    if (t == 511) rp[ROWS_TOTAL] = sh[511];     // grand total = 2*N_EDGES
}

// passA: per-WG counting sort of a 2048-edge chunk into bucket-grouped bursts
__global__ __launch_bounds__(256) void passA(const int* __restrict__ eu,
                                             const int* __restrict__ ei,
                                             const float* __restrict__ vals,
                                             int* __restrict__ bucket_cur,
                                             int2* __restrict__ edgesA, int n) {
    __shared__ int hist[NB];
    __shared__ int lbase[NB];
    __shared__ int lcur[NB];
    __shared__ int gbase[NB];
    __shared__ int2 stage[ENT_PER_WG];
    __shared__ unsigned short sbkt[ENT_PER_WG];
    __shared__ int scan_tmp[256];

    int t = threadIdx.x;
    int e0 = blockIdx.x * CHUNK_E;
    for (int i = t; i < NB; i += 256) hist[i] = 0;
    __syncthreads();

    int myu[8], myi[8];
    float myv[8];
#pragma unroll
    for (int j = 0; j < 8; ++j) {
        int e = e0 + j * 256 + t;
        if (e < n) {
            myu[j] = eu[e]; myi[j] = ei[e]; myv[j] = vals[e];
            atomicAdd(&hist[myu[j] >> 9], 1);
            atomicAdd(&hist[(myi[j] + USER_NUM) >> 9], 1);
        } else myu[j] = -1;
    }
    __syncthreads();

    // exclusive scan hist[NB] (256 threads x 2 slots)
    int a0 = (2 * t     < NB) ? hist[2 * t]     : 0;
    int a1 = (2 * t + 1 < NB) ? hist[2 * t + 1] : 0;
    scan_tmp[t] = a0 + a1;
    __syncthreads();
    for (int off = 1; off < 256; off <<= 1) {
        int x = (t >= off) ? scan_tmp[t - off] : 0;
        __syncthreads();
        scan_tmp[t] += x;
        __syncthreads();
    }
    int tb = (t == 0) ? 0 : scan_tmp[t - 1];
    if (2 * t < NB)     { lbase[2 * t] = tb;          lcur[2 * t] = 0; }
    if (2 * t + 1 < NB) { lbase[2 * t + 1] = tb + a0; lcur[2 * t + 1] = 0; }
    __syncthreads();

    // place entries into stage (both directions per edge)
#pragma unroll
    for (int j = 0; j < 8; ++j) {
        if (myu[j] >= 0) {
            int vb = __float_as_int(myv[j]);
            int row = myu[j];
            int b = row >> 9;
            int x = ((row & 511) << 17) | myi[j];   // col = item index (<2^17)
            int p = lbase[b] + atomicAdd(&lcur[b], 1);
            stage[p] = make_int2(x, vb); sbkt[p] = (unsigned short)b;

            row = myi[j] + USER_NUM;
            b = row >> 9;
            x = ((row & 511) << 17) | myu[j];       // col = user index (<2^17)
            p = lbase[b] + atomicAdd(&lcur[b], 1);
            stage[p] = make_int2(x, vb); sbkt[p] = (unsigned short)b;
        }
    }
    __syncthreads();

    // reserve global ranges (one atomic per non-empty bucket)
    for (int b = t; b < NB; b += 256) {
        int nb = hist[b];
        gbase[b] = nb ? atomicAdd(&bucket_cur[b], nb) : 0;
    }
    __syncthreads();

    // burst-write grouped entries
    int nedge = n - e0; if (nedge > CHUNK_E) nedge = CHUNK_E;
    int total = 2 * nedge;
    for (int s = t; s < total; s += 256) {
        int b = sbkt[s];
        edgesA[gbase[b] + (s - lbase[b])] = stage[s];
    }
}

// passB: one WG per bucket; sort bucket entries by row, emit rp for its rows
__global__ __launch_bounds__(256) void passB(const int2* __restrict__ edgesA,
                                             const int* __restrict__ brp,
                                             int* __restrict__ rp,
                                             int2* __restrict__ edgesB) {
    __shared__ int lcnt[BROWS];
    __shared__ int lbase[BROWS];
    __shared__ int scan_tmp[256];
    int b = blockIdx.x, t = threadIdx.x;
    int s0 = brp[b], s1 = brp[b + 1];
    for (int i = t; i < BROWS; i += 256) lcnt[i] = 0;
    __syncthreads();
    for (int s = s0 + t; s < s1; s += 256)
        atomicAdd(&lcnt[edgesA[s].x >> 17], 1);
    __syncthreads();
    // exclusive scan over 512 rows (256 threads x 2)
    int a0 = lcnt[2 * t], a1 = lcnt[2 * t + 1];
    scan_tmp[t] = a0 + a1;
    __syncthreads();
    for (int off = 1; off < 256; off <<= 1) {
        int x = (t >= off) ? scan_tmp[t - off] : 0;
        __syncthreads();
        scan_tmp[t] += x;
        __syncthreads();
    }
    int tb = (t == 0) ? 0 : scan_tmp[t - 1];
    lbase[2 * t] = tb;
    lbase[2 * t + 1] = tb + a0;
    __syncthreads();
    // emit rp for this bucket's rows
    int row0 = b * BROWS;
    for (int r = t; r < BROWS; r += 256) {
        int gr = row0 + r;
        if (gr < ROWS_TOTAL) rp[gr] = s0 + lbase[r];
    }
    for (int i = t; i < BROWS; i += 256) lcnt[i] = 0;  // reuse as cursors
    __syncthreads();
    for (int s = s0 + t; s < s1; s += 256) {
        int2 ent = edgesA[s];
        int rl = ent.x >> 17;
        int pos = s0 + lbase[rl] + atomicAdd(&lcnt[rl], 1);
        edgesB[pos] = ent;
    }
}

// unified gather: rows [0,USER_NUM) are users, [USER_NUM,ROWS_TOTAL) items
__global__ void spmm_gather(const unsigned short* __restrict__ ut,
                            const unsigned short* __restrict__ it,
                            const float* __restrict__ d_i, const float* __restrict__ d_j,
                            const int2* __restrict__ edges, const int* __restrict__ rp,
                            unsigned short* __restrict__ uo, unsigned short* __restrict__ io) {
    int r = blockIdx.x * (blockDim.x >> 6) + (threadIdx.x >> 6);
    if (r >= ROWS_TOTAL) return;
    int lane = threadIdx.x & 63;
    bool isU = r < USER_NUM;
    const unsigned short* xsrc  = isU ? it : ut;
    const unsigned short* xself = isU ? ut : it;
    int selfrow = isU ? r : r - USER_NUM;
    float dsc = isU ? d_i[r] : d_j[r - USER_NUM];
    float acc = dsc * bf2f(xself[(size_t)selfrow * FDIM + lane]);
    int e = rp[r], e2 = rp[r + 1];
    for (; e + 3 < e2; e += 4) {
        int2 a = edges[e], b = edges[e + 1], c = edges[e + 2], d = edges[e + 3];
        float x0 = bf2f(xsrc[(size_t)(a.x & 0x1FFFF) * FDIM + lane]);
        float x1 = bf2f(xsrc[(size_t)(b.x & 0x1FFFF) * FDIM + lane]);
        float x2 = bf2f(xsrc[(size_t)(c.x & 0x1FFFF) * FDIM + lane]);
        float x3 = bf2f(xsrc[(size_t)(d.x & 0x1FFFF) * FDIM + lane]);
        acc = fmaf(__int_as_float(a.y), x0, acc);
        acc = fmaf(__int_as_float(b.y), x1, acc);
        acc = fmaf(__int_as_float(c.y), x2, acc);
        acc = fmaf(__int_as_float(d.y), x3, acc);
    }
    for (; e < e2; ++e) {
        int2 a = edges[e];
        acc = fmaf(__int_as_float(a.y), bf2f(xsrc[(size_t)(a.x & 0x1FFFF) * FDIM + lane]), acc);
    }
    unsigned short* outp = isU ? uo : io;
    outp[(size_t)selfrow * FDIM + lane] = f2bf(acc);
}

__global__ void batch_pred(const unsigned short* __restrict__ u0, const unsigned short* __restrict__ u1,
                           const unsigned short* __restrict__ u2, const unsigned short* __restrict__ u3,
                           const unsigned short* __restrict__ i0, const unsigned short* __restrict__ i1,
                           const unsigned short* __restrict__ i2, const unsigned short* __restrict__ i3,
                           const int* __restrict__ user, const int* __restrict__ item_i,
                           const int* __restrict__ item_j,
                           float* __restrict__ pred_i, float* __restrict__ pred_j,
                           float* __restrict__ l2_terms, float* __restrict__ lsg_terms) {
    int b = blockIdx.x * (blockDim.x >> 6) + (threadIdx.x >> 6);
    if (b >= BATCH) return;
    int lane = threadIdx.x & 63;
    int uu = user[b], ii = item_i[b], ij = item_j[b];
    const unsigned short* U[4] = {u0, u1, u2, u3};
    const unsigned short* I[4] = {i0, i1, i2, i3};
    float pi = 0.f, pj = 0.f, l2 = 0.f;
#pragma unroll
    for (int k = 0; k < 4; ++k) {
        float ue = bf2f(U[k][(size_t)uu * FDIM + lane]);
        float vi = bf2f(I[k][(size_t)ii * FDIM + lane]);
        float vj = bf2f(I[k][(size_t)ij * FDIM + lane]);
        pi += ue * vi;
        pj += ue * vj;
        l2 += ue * ue + vi * vi + vj * vj;
    }
#pragma unroll
    for (int m = 32; m >= 1; m >>= 1) {
        pi += __shfl_xor(pi, m, 64);
        pj += __shfl_xor(pj, m, 64);
        l2 += __shfl_xor(l2, m, 64);
    }
    if (lane == 0) {
        pred_i[b] = pi;
        pred_j[b] = pj;
        l2_terms[b] = 0.01f * l2;
        float x = pi - pj;
        lsg_terms[b] = fminf(x, 0.f) - log1pf(expf(-fabsf(x)));
    }
}

__global__ void final_reduce(const float* __restrict__ l2_terms,
                             const float* __restrict__ lsg_terms,
                             float* __restrict__ out_loss, float* __restrict__ out_loss2) {
    __shared__ float s1[256];
    __shared__ float s2[256];
    int t = threadIdx.x;
    float a = 0.f, b = 0.f;
    for (int i = t; i < BATCH; i += 256) { a += l2_terms[i]; b += lsg_terms[i]; }
    s1[t] = a; s2[t] = b;
    __syncthreads();
    for (int s = 128; s >= 1; s >>= 1) {
        if (t < s) { s1[t] += s1[t + s]; s2[t] += s2[t + s]; }
        __syncthreads();
    }
    if (t == 0) {
        float loss2 = -s2[0] / (float)BATCH;
        *out_loss = loss2 + s1[0] / (float)BATCH;
        *out_loss2 = loss2;
    }
}

extern "C" void kernel_launch(void* const* d_in, const int* in_sizes, int n_in,
                              void* d_out, int out_size, void* d_ws, size_t ws_size,
                              hipStream_t stream) {
    const float* eu      = (const float*)d_in[0];
    const float* ei      = (const float*)d_in[1];
    const float* d_i     = (const float*)d_in[2];
    const float* d_j     = (const float*)d_in[3];
    const float* vals    = (const float*)d_in[4];
    const int*   e_users = (const int*)d_in[5];
    const int*   e_items = (const int*)d_in[6];
    const int*   user    = (const int*)d_in[7];
    const int*   item_i  = (const int*)d_in[8];
    const int*   item_j  = (const int*)d_in[9];

    // ---- workspace layout (4-byte words, all region sizes even -> 8B aligned) ----
    float* ws = (float*)d_ws;
    size_t off = 0;
    const size_t UW = (size_t)USER_NUM * FDIM / 2;
    const size_t IW = (size_t)ITEM_NUM * FDIM / 2;
    unsigned short* ub[4];
    unsigned short* ib[4];
    for (int k = 0; k < 4; ++k) { ub[k] = (unsigned short*)(ws + off); off += UW; }
    for (int k = 0; k < 4; ++k) { ib[k] = (unsigned short*)(ws + off); off += IW; }
    float* l2t  = ws + off; off += BATCH;
    float* lsgt = ws + off; off += BATCH;
    int* bcnt       = (int*)(ws + off); off += 512;
    int* brp        = (int*)(ws + off); off += 512;
    int* bucket_cur = (int*)(ws + off); off += 512;
    int* rp         = (int*)(ws + off); off += ROWS_TOTAL + 16;
    int2* edgesA = (int2*)(ws + off); off += (size_t)4 * N_EDGES;
    int2* edgesB = (int2*)(ws + off); off += (size_t)4 * N_EDGES;

    float* outp   = (float*)d_out;
    float* pred_i = outp;
    float* pred_j = outp + BATCH;
    float* loss   = outp + 2 * BATCH;
    float* loss2  = loss + 1;

    dim3 blk(256);

    // bf16 copies of layer-0 tables
    int nU4 = USER_NUM * FDIM / 4, nI4 = ITEM_NUM * FDIM / 4;
    f32_to_bf16_k<<<(nU4 + 255) / 256, blk, 0, stream>>>(eu, ub[0], nU4);
    f32_to_bf16_k<<<(nI4 + 255) / 256, blk, 0, stream>>>(ei, ib[0], nI4);

    // CSR build: bucket hist -> scan -> bucketize -> per-bucket row sort
    zero_ints<<<1, 512, 0, stream>>>(bcnt, NB);
    bucket_hist<<<768, blk, 0, stream>>>(e_users, e_items, bcnt, N_EDGES);
    bucket_scan<<<1, 512, 0, stream>>>(bcnt, brp, bucket_cur, rp);
    passA<<<(N_EDGES + CHUNK_E - 1) / CHUNK_E, blk, 0, stream>>>(
        e_users, e_items, vals, bucket_cur, edgesA, N_EDGES);
    passB<<<NB, blk, 0, stream>>>(edgesA, brp, rp, edgesB);

    // 3 propagation layers, unified gather (both directions per launch)
    int gridG = (ROWS_TOTAL + 3) / 4;
    for (int k = 0; k < 3; ++k) {
        spmm_gather<<<gridG, blk, 0, stream>>>(ub[k], ib[k], d_i, d_j,
                                               edgesB, rp, ub[k + 1], ib[k + 1]);
    }

    batch_pred<<<(BATCH + 3) / 4, blk, 0, stream>>>(
        ub[0], ub[1], ub[2], ub[3], ib[0], ib[1], ib[2], ib[3],
        user, item_i, item_j, pred_i, pred_j, l2t, lsgt);
    final_reduce<<<1, 256, 0, stream>>>(l2t, lsgt, loss, loss2);
}

// Round 6
// 414.995 us; speedup vs baseline: 5.1160x; 1.2152x over previous
//
#include <hip/hip_runtime.h>

#define USER_NUM 100000
#define ITEM_NUM 50000
#define FDIM 64
#define N_EDGES 1600000
#define BATCH 4096
#define ROWS_TOTAL (USER_NUM + ITEM_NUM)   // unified rows: users then items
#define BROWS 512                           // rows per bucket
#define NB ((ROWS_TOTAL + BROWS - 1) / BROWS)  // 293
#define CHUNK_E 2048                        // edges per passA WG
#define ENT_PER_WG (2 * CHUNK_E)
#define NKEY (BROWS * 16)                   // (localrow, col>>13) keys = 8192

__device__ __forceinline__ unsigned short f2bf(float f) {
    unsigned u = __float_as_uint(f);
    unsigned r = (u + 0x7FFFu + ((u >> 16) & 1u)) >> 16;  // RNE
    return (unsigned short)r;
}
__device__ __forceinline__ float bf2f(unsigned short h) {
    return __uint_as_float(((unsigned)h) << 16);
}

__global__ void zero_ints(int* __restrict__ a, int n) {
    int i = blockIdx.x * blockDim.x + threadIdx.x;
    if (i < n) a[i] = 0;
}

__global__ void f32_to_bf16_k(const float* __restrict__ x, unsigned short* __restrict__ y, int n4) {
    int i = blockIdx.x * blockDim.x + threadIdx.x;
    if (i >= n4) return;
    float4 v = reinterpret_cast<const float4*>(x)[i];
    reinterpret_cast<ushort4*>(y)[i] =
        make_ushort4(f2bf(v.x), f2bf(v.y), f2bf(v.z), f2bf(v.w));
}

__global__ void bucket_hist(const int* __restrict__ eu, const int* __restrict__ ei,
                            int* __restrict__ bcnt, int n) {
    __shared__ int h[NB];
    int t = threadIdx.x;
    for (int i = t; i < NB; i += 256) h[i] = 0;
    __syncthreads();
    for (int e = blockIdx.x * blockDim.x + t; e < n; e += gridDim.x * blockDim.x) {
        atomicAdd(&h[eu[e] >> 9], 1);
        atomicAdd(&h[(ei[e] + USER_NUM) >> 9], 1);
    }
    __syncthreads();
    for (int i = t; i < NB; i += 256)
        if (h[i]) atomicAdd(&bcnt[i], h[i]);
}

__global__ void bucket_scan(const int* __restrict__ bcnt, int* __restrict__ brp,
                            int* __restrict__ bucket_cur, int* __restrict__ rp) {
    __shared__ int sh[512];
    int t = threadIdx.x;
    int v = (t < NB) ? bcnt[t] : 0;
    sh[t] = v;
    __syncthreads();
    for (int off = 1; off < 512; off <<= 1) {
        int x = (t >= off) ? sh[t - off] : 0;
        __syncthreads();
        sh[t] += x;
        __syncthreads();
    }
    int ex = (t == 0) ? 0 : sh[t - 1];
    if (t < NB) { brp[t] = ex; bucket_cur[t] = ex; }
    if (t == NB) brp[NB] = ex;
    if (t == 511) rp[ROWS_TOTAL] = sh[511];
}

// passA: per-WG counting sort of 2048 edges into bucket-grouped burst writes
__global__ __launch_bounds__(256) void passA(const int* __restrict__ eu,
                                             const int* __restrict__ ei,
                                             const float* __restrict__ vals,
                                             int* __restrict__ bucket_cur,
                                             int2* __restrict__ edgesA, int n) {
    __shared__ int hist[NB];
    __shared__ int lbase[NB];
    __shared__ int lcur[NB];
    __shared__ int gbase[NB];
    __shared__ int2 stage[ENT_PER_WG];
    __shared__ unsigned short sbkt[ENT_PER_WG];
    __shared__ int scan_tmp[256];

    int t = threadIdx.x;
    int e0 = blockIdx.x * CHUNK_E;
    for (int i = t; i < NB; i += 256) hist[i] = 0;
    __syncthreads();

    int myu[8], myi[8];
    float myv[8];
#pragma unroll
    for (int j = 0; j < 8; ++j) {
        int e = e0 + j * 256 + t;
        if (e < n) {
            myu[j] = eu[e]; myi[j] = ei[e]; myv[j] = vals[e];
            atomicAdd(&hist[myu[j] >> 9], 1);
            atomicAdd(&hist[(myi[j] + USER_NUM) >> 9], 1);
        } else myu[j] = -1;
    }
    __syncthreads();

    int a0 = (2 * t     < NB) ? hist[2 * t]     : 0;
    int a1 = (2 * t + 1 < NB) ? hist[2 * t + 1] : 0;
    scan_tmp[t] = a0 + a1;
    __syncthreads();
    for (int off = 1; off < 256; off <<= 1) {
        int x = (t >= off) ? scan_tmp[t - off] : 0;
        __syncthreads();
        scan_tmp[t] += x;
        __syncthreads();
    }
    int tb = (t == 0) ? 0 : scan_tmp[t - 1];
    if (2 * t < NB)     { lbase[2 * t] = tb;          lcur[2 * t] = 0; }
    if (2 * t + 1 < NB) { lbase[2 * t + 1] = tb + a0; lcur[2 * t + 1] = 0; }
    __syncthreads();

#pragma unroll
    for (int j = 0; j < 8; ++j) {
        if (myu[j] >= 0) {
            int vb = __float_as_int(myv[j]);
            int row = myu[j];
            int b = row >> 9;
            int x = ((row & 511) << 17) | myi[j];
            int p = lbase[b] + atomicAdd(&lcur[b], 1);
            stage[p] = make_int2(x, vb); sbkt[p] = (unsigned short)b;

            row = myi[j] + USER_NUM;
            b = row >> 9;
            x = ((row & 511) << 17) | myu[j];
            p = lbase[b] + atomicAdd(&lcur[b], 1);
            stage[p] = make_int2(x, vb); sbkt[p] = (unsigned short)b;
        }
    }
    __syncthreads();

    for (int b = t; b < NB; b += 256) {
        int nb = hist[b];
        gbase[b] = nb ? atomicAdd(&bucket_cur[b], nb) : 0;
    }
    __syncthreads();

    int nedge = n - e0; if (nedge > CHUNK_E) nedge = CHUNK_E;
    int total = 2 * nedge;
    for (int s = t; s < total; s += 256) {
        int b = sbkt[s];
        edgesA[gbase[b] + (s - lbase[b])] = stage[s];
    }
}

// passB: one WG per bucket; sort by (localrow, col>>13) so each row's edge
// list is coarsely column-ordered -> concurrent gather waves sweep a narrow,
// L2-resident column window. Emits per-row rp.
__global__ __launch_bounds__(256) void passB(const int2* __restrict__ edgesA,
                                             const int* __restrict__ brp,
                                             int* __restrict__ rp,
                                             int2* __restrict__ edgesB) {
    __shared__ int lbase[NKEY];
    __shared__ int scan_tmp[256];
    int b = blockIdx.x, t = threadIdx.x;
    int s0 = brp[b], s1 = brp[b + 1];
    for (int i = t; i < NKEY; i += 256) lbase[i] = 0;
    __syncthreads();
    for (int s = s0 + t; s < s1; s += 256) {
        int x = edgesA[s].x;
        int key = ((x >> 17) << 4) | ((x & 0x1FFFF) >> 13);
        atomicAdd(&lbase[key], 1);
    }
    __syncthreads();
    // exclusive scan over NKEY (32 keys per thread, statically indexed)
    int base = t * 32;
    int vloc[32];
    int sum = 0;
#pragma unroll
    for (int j = 0; j < 32; ++j) { vloc[j] = lbase[base + j]; sum += vloc[j]; }
    scan_tmp[t] = sum;
    __syncthreads();
    for (int off = 1; off < 256; off <<= 1) {
        int x = (t >= off) ? scan_tmp[t - off] : 0;
        __syncthreads();
        scan_tmp[t] += x;
        __syncthreads();
    }
    int run = (t == 0) ? 0 : scan_tmp[t - 1];
#pragma unroll
    for (int j = 0; j < 32; ++j) { lbase[base + j] = run; run += vloc[j]; }
    __syncthreads();
    // emit rp (row start = first key of the row), BEFORE cursors mutate
    int row0 = b * BROWS;
    for (int r = t; r < BROWS; r += 256) {
        int gr = row0 + r;
        if (gr < ROWS_TOTAL) rp[gr] = s0 + lbase[r << 4];
    }
    __syncthreads();
    // scatter; lbase doubles as cursor
    for (int s = s0 + t; s < s1; s += 256) {
        int2 ent = edgesA[s];
        int x = ent.x;
        int key = ((x >> 17) << 4) | ((x & 0x1FFFF) >> 13);
        int pos = s0 + atomicAdd(&lbase[key], 1);
        edgesB[pos] = ent;
    }
}

// unified full gather for layers 1 and 2
__global__ void spmm_gather(const unsigned short* __restrict__ ut,
                            const unsigned short* __restrict__ it,
                            const float* __restrict__ d_i, const float* __restrict__ d_j,
                            const int2* __restrict__ edges, const int* __restrict__ rp,
                            unsigned short* __restrict__ uo, unsigned short* __restrict__ io) {
    int r = blockIdx.x * (blockDim.x >> 6) + (threadIdx.x >> 6);
    if (r >= ROWS_TOTAL) return;
    int lane = threadIdx.x & 63;
    bool isU = r < USER_NUM;
    const unsigned short* xsrc  = isU ? it : ut;
    const unsigned short* xself = isU ? ut : it;
    int selfrow = isU ? r : r - USER_NUM;
    float dsc = isU ? d_i[r] : d_j[r - USER_NUM];
    float acc = dsc * bf2f(xself[(size_t)selfrow * FDIM + lane]);
    int e = rp[r], e2 = rp[r + 1];
    for (; e + 3 < e2; e += 4) {
        int2 a = edges[e], b = edges[e + 1], c = edges[e + 2], d = edges[e + 3];
        float x0 = bf2f(xsrc[(size_t)(a.x & 0x1FFFF) * FDIM + lane]);
        float x1 = bf2f(xsrc[(size_t)(b.x & 0x1FFFF) * FDIM + lane]);
        float x2 = bf2f(xsrc[(size_t)(c.x & 0x1FFFF) * FDIM + lane]);
        float x3 = bf2f(xsrc[(size_t)(d.x & 0x1FFFF) * FDIM + lane]);
        acc = fmaf(__int_as_float(a.y), x0, acc);
        acc = fmaf(__int_as_float(b.y), x1, acc);
        acc = fmaf(__int_as_float(c.y), x2, acc);
        acc = fmaf(__int_as_float(d.y), x3, acc);
    }
    for (; e < e2; ++e) {
        int2 a = edges[e];
        acc = fmaf(__int_as_float(a.y), bf2f(xsrc[(size_t)(a.x & 0x1FFFF) * FDIM + lane]), acc);
    }
    unsigned short* outp = isU ? uo : io;
    outp[(size_t)selfrow * FDIM + lane] = f2bf(acc);
}

// per-row partial layer-3 gather: acc = dsc*self2 + sum val*src2[col]
__device__ __forceinline__ float layer3_row(const unsigned short* __restrict__ src2,
                                            float dsc, float self2,
                                            const int2* __restrict__ edges,
                                            int e, int e2, int lane) {
    float acc = dsc * self2;
    for (; e + 1 < e2; e += 2) {
        int2 a = edges[e], b = edges[e + 1];
        float x0 = bf2f(src2[(size_t)(a.x & 0x1FFFF) * FDIM + lane]);
        float x1 = bf2f(src2[(size_t)(b.x & 0x1FFFF) * FDIM + lane]);
        acc = fmaf(__int_as_float(a.y), x0, acc);
        acc = fmaf(__int_as_float(b.y), x1, acc);
    }
    if (e < e2) {
        int2 a = edges[e];
        acc = fmaf(__int_as_float(a.y), bf2f(src2[(size_t)(a.x & 0x1FFFF) * FDIM + lane]), acc);
    }
    return acc;
}

// fused head: computes layer-3 rows on the fly (only batch rows need them)
__global__ void batch_pred_fused(const unsigned short* __restrict__ u0,
                                 const unsigned short* __restrict__ u1,
                                 const unsigned short* __restrict__ u2,
                                 const unsigned short* __restrict__ i0,
                                 const unsigned short* __restrict__ i1,
                                 const unsigned short* __restrict__ i2,
                                 const float* __restrict__ d_i, const float* __restrict__ d_j,
                                 const int2* __restrict__ edges, const int* __restrict__ rp,
                                 const int* __restrict__ user, const int* __restrict__ item_i,
                                 const int* __restrict__ item_j,
                                 float* __restrict__ pred_i, float* __restrict__ pred_j,
                                 float* __restrict__ l2_terms, float* __restrict__ lsg_terms) {
    int b = blockIdx.x * (blockDim.x >> 6) + (threadIdx.x >> 6);
    if (b >= BATCH) return;
    int lane = threadIdx.x & 63;
    int uu = user[b], ii = item_i[b], ij = item_j[b];

    float ue0 = bf2f(u0[(size_t)uu * FDIM + lane]);
    float ue1 = bf2f(u1[(size_t)uu * FDIM + lane]);
    float ue2 = bf2f(u2[(size_t)uu * FDIM + lane]);
    float vi0 = bf2f(i0[(size_t)ii * FDIM + lane]);
    float vi1 = bf2f(i1[(size_t)ii * FDIM + lane]);
    float vi2 = bf2f(i2[(size_t)ii * FDIM + lane]);
    float vj0 = bf2f(i0[(size_t)ij * FDIM + lane]);
    float vj1 = bf2f(i1[(size_t)ij * FDIM + lane]);
    float vj2 = bf2f(i2[(size_t)ij * FDIM + lane]);

    // layer-3 rows (reference rounds u3/i3 through nothing; we keep f32)
    float ue3 = layer3_row(i2, d_i[uu], ue2, edges, rp[uu], rp[uu + 1], lane);
    int ri = USER_NUM + ii, rj = USER_NUM + ij;
    float vi3 = layer3_row(u2, d_j[ii], vi2, edges, rp[ri], rp[ri + 1], lane);
    float vj3 = layer3_row(u2, d_j[ij], vj2, edges, rp[rj], rp[rj + 1], lane);

    float pi = ue0 * vi0 + ue1 * vi1 + ue2 * vi2 + ue3 * vi3;
    float pj = ue0 * vj0 + ue1 * vj1 + ue2 * vj2 + ue3 * vj3;
    float l2 = ue0 * ue0 + ue1 * ue1 + ue2 * ue2 + ue3 * ue3
             + vi0 * vi0 + vi1 * vi1 + vi2 * vi2 + vi3 * vi3
             + vj0 * vj0 + vj1 * vj1 + vj2 * vj2 + vj3 * vj3;
#pragma unroll
    for (int m = 32; m >= 1; m >>= 1) {
        pi += __shfl_xor(pi, m, 64);
        pj += __shfl_xor(pj, m, 64);
        l2 += __shfl_xor(l2, m, 64);
    }
    if (lane == 0) {
        pred_i[b] = pi;
        pred_j[b] = pj;
        l2_terms[b] = 0.01f * l2;
        float x = pi - pj;
        lsg_terms[b] = fminf(x, 0.f) - log1pf(expf(-fabsf(x)));
    }
}

__global__ void final_reduce(const float* __restrict__ l2_terms,
                             const float* __restrict__ lsg_terms,
                             float* __restrict__ out_loss, float* __restrict__ out_loss2) {
    __shared__ float s1[256];
    __shared__ float s2[256];
    int t = threadIdx.x;
    float a = 0.f, b = 0.f;
    for (int i = t; i < BATCH; i += 256) { a += l2_terms[i]; b += lsg_terms[i]; }
    s1[t] = a; s2[t] = b;
    __syncthreads();
    for (int s = 128; s >= 1; s >>= 1) {
        if (t < s) { s1[t] += s1[t + s]; s2[t] += s2[t + s]; }
        __syncthreads();
    }
    if (t == 0) {
        float loss2 = -s2[0] / (float)BATCH;
        *out_loss = loss2 + s1[0] / (float)BATCH;
        *out_loss2 = loss2;
    }
}

extern "C" void kernel_launch(void* const* d_in, const int* in_sizes, int n_in,
                              void* d_out, int out_size, void* d_ws, size_t ws_size,
                              hipStream_t stream) {
    const float* eu      = (const float*)d_in[0];
    const float* ei      = (const float*)d_in[1];
    const float* d_i     = (const float*)d_in[2];
    const float* d_j     = (const float*)d_in[3];
    const float* vals    = (const float*)d_in[4];
    const int*   e_users = (const int*)d_in[5];
    const int*   e_items = (const int*)d_in[6];
    const int*   user    = (const int*)d_in[7];
    const int*   item_i  = (const int*)d_in[8];
    const int*   item_j  = (const int*)d_in[9];

    float* ws = (float*)d_ws;
    size_t off = 0;
    const size_t UW = (size_t)USER_NUM * FDIM / 2;
    const size_t IW = (size_t)ITEM_NUM * FDIM / 2;
    unsigned short* ub[3];
    unsigned short* ib[3];
    for (int k = 0; k < 3; ++k) { ub[k] = (unsigned short*)(ws + off); off += UW; }
    for (int k = 0; k < 3; ++k) { ib[k] = (unsigned short*)(ws + off); off += IW; }
    float* l2t  = ws + off; off += BATCH;
    float* lsgt = ws + off; off += BATCH;
    int* bcnt       = (int*)(ws + off); off += 512;
    int* brp        = (int*)(ws + off); off += 512;
    int* bucket_cur = (int*)(ws + off); off += 512;
    int* rp         = (int*)(ws + off); off += ROWS_TOTAL + 16;
    int2* edgesA = (int2*)(ws + off); off += (size_t)4 * N_EDGES;
    int2* edgesB = (int2*)(ws + off); off += (size_t)4 * N_EDGES;

    float* outp   = (float*)d_out;
    float* pred_i = outp;
    float* pred_j = outp + BATCH;
    float* loss   = outp + 2 * BATCH;
    float* loss2  = loss + 1;

    dim3 blk(256);

    int nU4 = USER_NUM * FDIM / 4, nI4 = ITEM_NUM * FDIM / 4;
    f32_to_bf16_k<<<(nU4 + 255) / 256, blk, 0, stream>>>(eu, ub[0], nU4);
    f32_to_bf16_k<<<(nI4 + 255) / 256, blk, 0, stream>>>(ei, ib[0], nI4);

    zero_ints<<<1, 512, 0, stream>>>(bcnt, NB);
    bucket_hist<<<768, blk, 0, stream>>>(e_users, e_items, bcnt, N_EDGES);
    bucket_scan<<<1, 512, 0, stream>>>(bcnt, brp, bucket_cur, rp);
    passA<<<(N_EDGES + CHUNK_E - 1) / CHUNK_E, blk, 0, stream>>>(
        e_users, e_items, vals, bucket_cur, edgesA, N_EDGES);
    passB<<<NB, blk, 0, stream>>>(edgesA, brp, rp, edgesB);

    // layers 1 and 2, full gathers
    int gridG = (ROWS_TOTAL + 3) / 4;
    for (int k = 0; k < 2; ++k) {
        spmm_gather<<<gridG, blk, 0, stream>>>(ub[k], ib[k], d_i, d_j,
                                               edgesB, rp, ub[k + 1], ib[k + 1]);
    }

    // layer 3 computed only for batch rows, fused into the head
    batch_pred_fused<<<(BATCH + 3) / 4, blk, 0, stream>>>(
        ub[0], ub[1], ub[2], ib[0], ib[1], ib[2],
        d_i, d_j, edgesB, rp, user, item_i, item_j,
        pred_i, pred_j, l2t, lsgt);
    final_reduce<<<1, 256, 0, stream>>>(l2t, lsgt, loss, loss2);
}

// Round 7
// 336.519 us; speedup vs baseline: 6.3090x; 1.2332x over previous
//
#include <hip/hip_runtime.h>

#define USER_NUM 100000
#define ITEM_NUM 50000
#define FDIM 64
#define N_EDGES 1600000
#define BATCH 4096
#define ROWS_TOTAL (USER_NUM + ITEM_NUM)   // unified rows: users then items
#define BROWS 512                           // rows per bucket
#define NB ((ROWS_TOTAL + BROWS - 1) / BROWS)  // 293
#define CHUNK_E 2048                        // edges per passA WG
#define ENT_PER_WG (2 * CHUNK_E)

__device__ __forceinline__ unsigned short f2bf(float f) {
    unsigned u = __float_as_uint(f);
    unsigned r = (u + 0x7FFFu + ((u >> 16) & 1u)) >> 16;  // RNE
    return (unsigned short)r;
}
__device__ __forceinline__ float bf2f(unsigned short h) {
    return __uint_as_float(((unsigned)h) << 16);
}

__global__ void zero_ints(int* __restrict__ a, int n) {
    int i = blockIdx.x * blockDim.x + threadIdx.x;
    if (i < n) a[i] = 0;
}

__global__ void f32_to_bf16_k(const float* __restrict__ x, unsigned short* __restrict__ y, int n4) {
    int i = blockIdx.x * blockDim.x + threadIdx.x;
    if (i >= n4) return;
    float4 v = reinterpret_cast<const float4*>(x)[i];
    reinterpret_cast<ushort4*>(y)[i] =
        make_ushort4(f2bf(v.x), f2bf(v.y), f2bf(v.z), f2bf(v.w));
}

__global__ void bucket_hist(const int* __restrict__ eu, const int* __restrict__ ei,
                            int* __restrict__ bcnt, int n) {
    __shared__ int h[NB];
    int t = threadIdx.x;
    for (int i = t; i < NB; i += 256) h[i] = 0;
    __syncthreads();
    for (int e = blockIdx.x * blockDim.x + t; e < n; e += gridDim.x * blockDim.x) {
        atomicAdd(&h[eu[e] >> 9], 1);
        atomicAdd(&h[(ei[e] + USER_NUM) >> 9], 1);
    }
    __syncthreads();
    for (int i = t; i < NB; i += 256)
        if (h[i]) atomicAdd(&bcnt[i], h[i]);
}

__global__ void bucket_scan(const int* __restrict__ bcnt, int* __restrict__ brp,
                            int* __restrict__ bucket_cur, int* __restrict__ rp) {
    __shared__ int sh[512];
    int t = threadIdx.x;
    int v = (t < NB) ? bcnt[t] : 0;
    sh[t] = v;
    __syncthreads();
    for (int off = 1; off < 512; off <<= 1) {
        int x = (t >= off) ? sh[t - off] : 0;
        __syncthreads();
        sh[t] += x;
        __syncthreads();
    }
    int ex = (t == 0) ? 0 : sh[t - 1];
    if (t < NB) { brp[t] = ex; bucket_cur[t] = ex; }
    if (t == NB) brp[NB] = ex;
    if (t == 511) rp[ROWS_TOTAL] = sh[511];
}

// passA: per-WG counting sort of 2048 edges into bucket-grouped burst writes
__global__ __launch_bounds__(256) void passA(const int* __restrict__ eu,
                                             const int* __restrict__ ei,
                                             const float* __restrict__ vals,
                                             int* __restrict__ bucket_cur,
                                             int2* __restrict__ edgesA, int n) {
    __shared__ int hist[NB];
    __shared__ int lbase[NB];
    __shared__ int lcur[NB];
    __shared__ int gbase[NB];
    __shared__ int2 stage[ENT_PER_WG];
    __shared__ unsigned short sbkt[ENT_PER_WG];
    __shared__ int scan_tmp[256];

    int t = threadIdx.x;
    int e0 = blockIdx.x * CHUNK_E;
    for (int i = t; i < NB; i += 256) hist[i] = 0;
    __syncthreads();

    int myu[8], myi[8];
    float myv[8];
#pragma unroll
    for (int j = 0; j < 8; ++j) {
        int e = e0 + j * 256 + t;
        if (e < n) {
            myu[j] = eu[e]; myi[j] = ei[e]; myv[j] = vals[e];
            atomicAdd(&hist[myu[j] >> 9], 1);
            atomicAdd(&hist[(myi[j] + USER_NUM) >> 9], 1);
        } else myu[j] = -1;
    }
    __syncthreads();

    int a0 = (2 * t     < NB) ? hist[2 * t]     : 0;
    int a1 = (2 * t + 1 < NB) ? hist[2 * t + 1] : 0;
    scan_tmp[t] = a0 + a1;
    __syncthreads();
    for (int off = 1; off < 256; off <<= 1) {
        int x = (t >= off) ? scan_tmp[t - off] : 0;
        __syncthreads();
        scan_tmp[t] += x;
        __syncthreads();
    }
    int tb = (t == 0) ? 0 : scan_tmp[t - 1];
    if (2 * t < NB)     { lbase[2 * t] = tb;          lcur[2 * t] = 0; }
    if (2 * t + 1 < NB) { lbase[2 * t + 1] = tb + a0; lcur[2 * t + 1] = 0; }
    __syncthreads();

#pragma unroll
    for (int j = 0; j < 8; ++j) {
        if (myu[j] >= 0) {
            int vb = __float_as_int(myv[j]);
            int row = myu[j];
            int b = row >> 9;
            int x = ((row & 511) << 17) | myi[j];
            int p = lbase[b] + atomicAdd(&lcur[b], 1);
            stage[p] = make_int2(x, vb); sbkt[p] = (unsigned short)b;

            row = myi[j] + USER_NUM;
            b = row >> 9;
            x = ((row & 511) << 17) | myu[j];
            p = lbase[b] + atomicAdd(&lcur[b], 1);
            stage[p] = make_int2(x, vb); sbkt[p] = (unsigned short)b;
        }
    }
    __syncthreads();

    for (int b = t; b < NB; b += 256) {
        int nb = hist[b];
        gbase[b] = nb ? atomicAdd(&bucket_cur[b], nb) : 0;
    }
    __syncthreads();

    int nedge = n - e0; if (nedge > CHUNK_E) nedge = CHUNK_E;
    int total = 2 * nedge;
    for (int s = t; s < total; s += 256) {
        int b = sbkt[s];
        edgesA[gbase[b] + (s - lbase[b])] = stage[s];
    }
}

// passB: one WG per bucket; sort bucket entries by local row, emit per-row rp
__global__ __launch_bounds__(256) void passB(const int2* __restrict__ edgesA,
                                             const int* __restrict__ brp,
                                             int* __restrict__ rp,
                                             int2* __restrict__ edgesB) {
    __shared__ int lcnt[BROWS];
    __shared__ int lbase[BROWS];
    __shared__ int scan_tmp[256];
    int b = blockIdx.x, t = threadIdx.x;
    int s0 = brp[b], s1 = brp[b + 1];
    for (int i = t; i < BROWS; i += 256) lcnt[i] = 0;
    __syncthreads();
    for (int s = s0 + t; s < s1; s += 256)
        atomicAdd(&lcnt[edgesA[s].x >> 17], 1);
    __syncthreads();
    int a0 = lcnt[2 * t], a1 = lcnt[2 * t + 1];
    scan_tmp[t] = a0 + a1;
    __syncthreads();
    for (int off = 1; off < 256; off <<= 1) {
        int x = (t >= off) ? scan_tmp[t - off] : 0;
        __syncthreads();
        scan_tmp[t] += x;
        __syncthreads();
    }
    int tb = (t == 0) ? 0 : scan_tmp[t - 1];
    lbase[2 * t] = tb;
    lbase[2 * t + 1] = tb + a0;
    __syncthreads();
    int row0 = b * BROWS;
    for (int r = t; r < BROWS; r += 256) {
        int gr = row0 + r;
        if (gr < ROWS_TOTAL) rp[gr] = s0 + lbase[r];
    }
    for (int i = t; i < BROWS; i += 256) lcnt[i] = 0;  // reuse as cursors
    __syncthreads();
    for (int s = s0 + t; s < s1; s += 256) {
        int2 ent = edgesA[s];
        int rl = ent.x >> 17;
        int pos = s0 + lbase[rl] + atomicAdd(&lcnt[rl], 1);
        edgesB[pos] = ent;
    }
}

// unified full gather, 8-deep load pipelining for MLP
__global__ void spmm_gather(const unsigned short* __restrict__ ut,
                            const unsigned short* __restrict__ it,
                            const float* __restrict__ d_i, const float* __restrict__ d_j,
                            const int2* __restrict__ edges, const int* __restrict__ rp,
                            unsigned short* __restrict__ uo, unsigned short* __restrict__ io) {
    int r = blockIdx.x * (blockDim.x >> 6) + (threadIdx.x >> 6);
    if (r >= ROWS_TOTAL) return;
    int lane = threadIdx.x & 63;
    bool isU = r < USER_NUM;
    const unsigned short* xsrc  = isU ? it : ut;
    const unsigned short* xself = isU ? ut : it;
    int selfrow = isU ? r : r - USER_NUM;
    float dsc = isU ? d_i[r] : d_j[r - USER_NUM];
    float acc = dsc * bf2f(xself[(size_t)selfrow * FDIM + lane]);
    int e = rp[r], e2 = rp[r + 1];
    // 8-deep: issue all 8 gathers before any FMA
    for (; e + 7 < e2; e += 8) {
        int2 ed[8];
        float xv[8];
#pragma unroll
        for (int j = 0; j < 8; ++j) ed[j] = edges[e + j];
#pragma unroll
        for (int j = 0; j < 8; ++j)
            xv[j] = bf2f(xsrc[(size_t)(ed[j].x & 0x1FFFF) * FDIM + lane]);
#pragma unroll
        for (int j = 0; j < 8; ++j)
            acc = fmaf(__int_as_float(ed[j].y), xv[j], acc);
    }
    for (; e + 3 < e2; e += 4) {
        int2 ed[4];
        float xv[4];
#pragma unroll
        for (int j = 0; j < 4; ++j) ed[j] = edges[e + j];
#pragma unroll
        for (int j = 0; j < 4; ++j)
            xv[j] = bf2f(xsrc[(size_t)(ed[j].x & 0x1FFFF) * FDIM + lane]);
#pragma unroll
        for (int j = 0; j < 4; ++j)
            acc = fmaf(__int_as_float(ed[j].y), xv[j], acc);
    }
    for (; e < e2; ++e) {
        int2 a = edges[e];
        acc = fmaf(__int_as_float(a.y), bf2f(xsrc[(size_t)(a.x & 0x1FFFF) * FDIM + lane]), acc);
    }
    unsigned short* outp = isU ? uo : io;
    outp[(size_t)selfrow * FDIM + lane] = f2bf(acc);
}

// per-row partial layer-3 gather, 4-deep pipelined
__device__ __forceinline__ float layer3_row(const unsigned short* __restrict__ src2,
                                            float dsc, float self2,
                                            const int2* __restrict__ edges,
                                            int e, int e2, int lane) {
    float acc = dsc * self2;
    for (; e + 3 < e2; e += 4) {
        int2 ed[4];
        float xv[4];
#pragma unroll
        for (int j = 0; j < 4; ++j) ed[j] = edges[e + j];
#pragma unroll
        for (int j = 0; j < 4; ++j)
            xv[j] = bf2f(src2[(size_t)(ed[j].x & 0x1FFFF) * FDIM + lane]);
#pragma unroll
        for (int j = 0; j < 4; ++j)
            acc = fmaf(__int_as_float(ed[j].y), xv[j], acc);
    }
    for (; e < e2; ++e) {
        int2 a = edges[e];
        acc = fmaf(__int_as_float(a.y), bf2f(src2[(size_t)(a.x & 0x1FFFF) * FDIM + lane]), acc);
    }
    return acc;
}

// fused head: computes layer-3 rows on the fly (only batch rows need them)
__global__ void batch_pred_fused(const unsigned short* __restrict__ u0,
                                 const unsigned short* __restrict__ u1,
                                 const unsigned short* __restrict__ u2,
                                 const unsigned short* __restrict__ i0,
                                 const unsigned short* __restrict__ i1,
                                 const unsigned short* __restrict__ i2,
                                 const float* __restrict__ d_i, const float* __restrict__ d_j,
                                 const int2* __restrict__ edges, const int* __restrict__ rp,
                                 const int* __restrict__ user, const int* __restrict__ item_i,
                                 const int* __restrict__ item_j,
                                 float* __restrict__ pred_i, float* __restrict__ pred_j,
                                 float* __restrict__ l2_terms, float* __restrict__ lsg_terms) {
    int b = blockIdx.x * (blockDim.x >> 6) + (threadIdx.x >> 6);
    if (b >= BATCH) return;
    int lane = threadIdx.x & 63;
    int uu = user[b], ii = item_i[b], ij = item_j[b];

    float ue0 = bf2f(u0[(size_t)uu * FDIM + lane]);
    float ue1 = bf2f(u1[(size_t)uu * FDIM + lane]);
    float ue2 = bf2f(u2[(size_t)uu * FDIM + lane]);
    float vi0 = bf2f(i0[(size_t)ii * FDIM + lane]);
    float vi1 = bf2f(i1[(size_t)ii * FDIM + lane]);
    float vi2 = bf2f(i2[(size_t)ii * FDIM + lane]);
    float vj0 = bf2f(i0[(size_t)ij * FDIM + lane]);
    float vj1 = bf2f(i1[(size_t)ij * FDIM + lane]);
    float vj2 = bf2f(i2[(size_t)ij * FDIM + lane]);

    float ue3 = layer3_row(i2, d_i[uu], ue2, edges, rp[uu], rp[uu + 1], lane);
    int ri = USER_NUM + ii, rj = USER_NUM + ij;
    float vi3 = layer3_row(u2, d_j[ii], vi2, edges, rp[ri], rp[ri + 1], lane);
    float vj3 = layer3_row(u2, d_j[ij], vj2, edges, rp[rj], rp[rj + 1], lane);

    float pi = ue0 * vi0 + ue1 * vi1 + ue2 * vi2 + ue3 * vi3;
    float pj = ue0 * vj0 + ue1 * vj1 + ue2 * vj2 + ue3 * vj3;
    float l2 = ue0 * ue0 + ue1 * ue1 + ue2 * ue2 + ue3 * ue3
             + vi0 * vi0 + vi1 * vi1 + vi2 * vi2 + vi3 * vi3
             + vj0 * vj0 + vj1 * vj1 + vj2 * vj2 + vj3 * vj3;
#pragma unroll
    for (int m = 32; m >= 1; m >>= 1) {
        pi += __shfl_xor(pi, m, 64);
        pj += __shfl_xor(pj, m, 64);
        l2 += __shfl_xor(l2, m, 64);
    }
    if (lane == 0) {
        pred_i[b] = pi;
        pred_j[b] = pj;
        l2_terms[b] = 0.01f * l2;
        float x = pi - pj;
        lsg_terms[b] = fminf(x, 0.f) - log1pf(expf(-fabsf(x)));
    }
}

__global__ void final_reduce(const float* __restrict__ l2_terms,
                             const float* __restrict__ lsg_terms,
                             float* __restrict__ out_loss, float* __restrict__ out_loss2) {
    __shared__ float s1[256];
    __shared__ float s2[256];
    int t = threadIdx.x;
    float a = 0.f, b = 0.f;
    for (int i = t; i < BATCH; i += 256) { a += l2_terms[i]; b += lsg_terms[i]; }
    s1[t] = a; s2[t] = b;
    __syncthreads();
    for (int s = 128; s >= 1; s >>= 1) {
        if (t < s) { s1[t] += s1[t + s]; s2[t] += s2[t + s]; }
        __syncthreads();
    }
    if (t == 0) {
        float loss2 = -s2[0] / (float)BATCH;
        *out_loss = loss2 + s1[0] / (float)BATCH;
        *out_loss2 = loss2;
    }
}

extern "C" void kernel_launch(void* const* d_in, const int* in_sizes, int n_in,
                              void* d_out, int out_size, void* d_ws, size_t ws_size,
                              hipStream_t stream) {
    const float* eu      = (const float*)d_in[0];
    const float* ei      = (const float*)d_in[1];
    const float* d_i     = (const float*)d_in[2];
    const float* d_j     = (const float*)d_in[3];
    const float* vals    = (const float*)d_in[4];
    const int*   e_users = (const int*)d_in[5];
    const int*   e_items = (const int*)d_in[6];
    const int*   user    = (const int*)d_in[7];
    const int*   item_i  = (const int*)d_in[8];
    const int*   item_j  = (const int*)d_in[9];

    float* ws = (float*)d_ws;
    size_t off = 0;
    const size_t UW = (size_t)USER_NUM * FDIM / 2;
    const size_t IW = (size_t)ITEM_NUM * FDIM / 2;
    unsigned short* ub[3];
    unsigned short* ib[3];
    for (int k = 0; k < 3; ++k) { ub[k] = (unsigned short*)(ws + off); off += UW; }
    for (int k = 0; k < 3; ++k) { ib[k] = (unsigned short*)(ws + off); off += IW; }
    float* l2t  = ws + off; off += BATCH;
    float* lsgt = ws + off; off += BATCH;
    int* bcnt       = (int*)(ws + off); off += 512;
    int* brp        = (int*)(ws + off); off += 512;
    int* bucket_cur = (int*)(ws + off); off += 512;
    int* rp         = (int*)(ws + off); off += ROWS_TOTAL + 16;
    int2* edgesA = (int2*)(ws + off); off += (size_t)4 * N_EDGES;
    int2* edgesB = (int2*)(ws + off); off += (size_t)4 * N_EDGES;

    float* outp   = (float*)d_out;
    float* pred_i = outp;
    float* pred_j = outp + BATCH;
    float* loss   = outp + 2 * BATCH;
    float* loss2  = loss + 1;

    dim3 blk(256);

    int nU4 = USER_NUM * FDIM / 4, nI4 = ITEM_NUM * FDIM / 4;
    f32_to_bf16_k<<<(nU4 + 255) / 256, blk, 0, stream>>>(eu, ub[0], nU4);
    f32_to_bf16_k<<<(nI4 + 255) / 256, blk, 0, stream>>>(ei, ib[0], nI4);

    zero_ints<<<1, 512, 0, stream>>>(bcnt, NB);
    bucket_hist<<<768, blk, 0, stream>>>(e_users, e_items, bcnt, N_EDGES);
    bucket_scan<<<1, 512, 0, stream>>>(bcnt, brp, bucket_cur, rp);
    passA<<<(N_EDGES + CHUNK_E - 1) / CHUNK_E, blk, 0, stream>>>(
        e_users, e_items, vals, bucket_cur, edgesA, N_EDGES);
    passB<<<NB, blk, 0, stream>>>(edgesA, brp, rp, edgesB);

    // layers 1 and 2, full gathers
    int gridG = (ROWS_TOTAL + 3) / 4;
    for (int k = 0; k < 2; ++k) {
        spmm_gather<<<gridG, blk, 0, stream>>>(ub[k], ib[k], d_i, d_j,
                                               edgesB, rp, ub[k + 1], ib[k + 1]);
    }

    // layer 3 computed only for batch rows, fused into the head
    batch_pred_fused<<<(BATCH + 3) / 4, blk, 0, stream>>>(
        ub[0], ub[1], ub[2], ib[0], ib[1], ib[2],
        d_i, d_j, edgesB, rp, user, item_i, item_j,
        pred_i, pred_j, l2t, lsgt);
    final_reduce<<<1, 256, 0, stream>>>(l2t, lsgt, loss, loss2);
}

// Round 8
// 330.276 us; speedup vs baseline: 6.4282x; 1.0189x over previous
//
#include <hip/hip_runtime.h>

#define USER_NUM 100000
#define ITEM_NUM 50000
#define FDIM 64
#define N_EDGES 1600000
#define BATCH 4096
#define ROWS_TOTAL (USER_NUM + ITEM_NUM)   // unified rows: users then items
#define BROWS 512                           // rows per bucket
#define NB ((ROWS_TOTAL + BROWS - 1) / BROWS)  // 293
#define CHUNK_E 2048                        // edges per passA WG
#define ENT_PER_WG (2 * CHUNK_E)

__device__ __forceinline__ unsigned short f2bf(float f) {
    unsigned u = __float_as_uint(f);
    unsigned r = (u + 0x7FFFu + ((u >> 16) & 1u)) >> 16;  // RNE
    return (unsigned short)r;
}
__device__ __forceinline__ float bf2f(unsigned short h) {
    return __uint_as_float(((unsigned)h) << 16);
}
__device__ __forceinline__ float bf2f_lo(unsigned u) {   // low ushort as bf16
    return __uint_as_float(u << 16);
}
__device__ __forceinline__ float bf2f_hi(unsigned u) {   // high ushort as bf16
    return __uint_as_float(u & 0xFFFF0000u);
}

__global__ void zero_ints(int* __restrict__ a, int n) {
    int i = blockIdx.x * blockDim.x + threadIdx.x;
    if (i < n) a[i] = 0;
}

__global__ void f32_to_bf16_k(const float* __restrict__ x, unsigned short* __restrict__ y, int n4) {
    int i = blockIdx.x * blockDim.x + threadIdx.x;
    if (i >= n4) return;
    float4 v = reinterpret_cast<const float4*>(x)[i];
    reinterpret_cast<ushort4*>(y)[i] =
        make_ushort4(f2bf(v.x), f2bf(v.y), f2bf(v.z), f2bf(v.w));
}

__global__ void bucket_hist(const int* __restrict__ eu, const int* __restrict__ ei,
                            int* __restrict__ bcnt, int n) {
    __shared__ int h[NB];
    int t = threadIdx.x;
    for (int i = t; i < NB; i += 256) h[i] = 0;
    __syncthreads();
    for (int e = blockIdx.x * blockDim.x + t; e < n; e += gridDim.x * blockDim.x) {
        atomicAdd(&h[eu[e] >> 9], 1);
        atomicAdd(&h[(ei[e] + USER_NUM) >> 9], 1);
    }
    __syncthreads();
    for (int i = t; i < NB; i += 256)
        if (h[i]) atomicAdd(&bcnt[i], h[i]);
}

__global__ void bucket_scan(const int* __restrict__ bcnt, int* __restrict__ brp,
                            int* __restrict__ bucket_cur, int* __restrict__ rp) {
    __shared__ int sh[512];
    int t = threadIdx.x;
    int v = (t < NB) ? bcnt[t] : 0;
    sh[t] = v;
    __syncthreads();
    for (int off = 1; off < 512; off <<= 1) {
        int x = (t >= off) ? sh[t - off] : 0;
        __syncthreads();
        sh[t] += x;
        __syncthreads();
    }
    int ex = (t == 0) ? 0 : sh[t - 1];
    if (t < NB) { brp[t] = ex; bucket_cur[t] = ex; }
    if (t == NB) brp[NB] = ex;
    if (t == 511) rp[ROWS_TOTAL] = sh[511];
}

// passA: per-WG counting sort of 2048 edges into bucket-grouped burst writes
__global__ __launch_bounds__(256) void passA(const int* __restrict__ eu,
                                             const int* __restrict__ ei,
                                             const float* __restrict__ vals,
                                             int* __restrict__ bucket_cur,
                                             int2* __restrict__ edgesA, int n) {
    __shared__ int hist[NB];
    __shared__ int lbase[NB];
    __shared__ int lcur[NB];
    __shared__ int gbase[NB];
    __shared__ int2 stage[ENT_PER_WG];
    __shared__ unsigned short sbkt[ENT_PER_WG];
    __shared__ int scan_tmp[256];

    int t = threadIdx.x;
    int e0 = blockIdx.x * CHUNK_E;
    for (int i = t; i < NB; i += 256) hist[i] = 0;
    __syncthreads();

    int myu[8], myi[8];
    float myv[8];
#pragma unroll
    for (int j = 0; j < 8; ++j) {
        int e = e0 + j * 256 + t;
        if (e < n) {
            myu[j] = eu[e]; myi[j] = ei[e]; myv[j] = vals[e];
            atomicAdd(&hist[myu[j] >> 9], 1);
            atomicAdd(&hist[(myi[j] + USER_NUM) >> 9], 1);
        } else myu[j] = -1;
    }
    __syncthreads();

    int a0 = (2 * t     < NB) ? hist[2 * t]     : 0;
    int a1 = (2 * t + 1 < NB) ? hist[2 * t + 1] : 0;
    scan_tmp[t] = a0 + a1;
    __syncthreads();
    for (int off = 1; off < 256; off <<= 1) {
        int x = (t >= off) ? scan_tmp[t - off] : 0;
        __syncthreads();
        scan_tmp[t] += x;
        __syncthreads();
    }
    int tb = (t == 0) ? 0 : scan_tmp[t - 1];
    if (2 * t < NB)     { lbase[2 * t] = tb;          lcur[2 * t] = 0; }
    if (2 * t + 1 < NB) { lbase[2 * t + 1] = tb + a0; lcur[2 * t + 1] = 0; }
    __syncthreads();

#pragma unroll
    for (int j = 0; j < 8; ++j) {
        if (myu[j] >= 0) {
            int vb = __float_as_int(myv[j]);
            int row = myu[j];
            int b = row >> 9;
            int x = ((row & 511) << 17) | myi[j];
            int p = lbase[b] + atomicAdd(&lcur[b], 1);
            stage[p] = make_int2(x, vb); sbkt[p] = (unsigned short)b;

            row = myi[j] + USER_NUM;
            b = row >> 9;
            x = ((row & 511) << 17) | myu[j];
            p = lbase[b] + atomicAdd(&lcur[b], 1);
            stage[p] = make_int2(x, vb); sbkt[p] = (unsigned short)b;
        }
    }
    __syncthreads();

    for (int b = t; b < NB; b += 256) {
        int nb = hist[b];
        gbase[b] = nb ? atomicAdd(&bucket_cur[b], nb) : 0;
    }
    __syncthreads();

    int nedge = n - e0; if (nedge > CHUNK_E) nedge = CHUNK_E;
    int total = 2 * nedge;
    for (int s = t; s < total; s += 256) {
        int b = sbkt[s];
        edgesA[gbase[b] + (s - lbase[b])] = stage[s];
    }
}

// passB: one WG per bucket; sort bucket entries by local row, emit per-row rp
__global__ __launch_bounds__(256) void passB(const int2* __restrict__ edgesA,
                                             const int* __restrict__ brp,
                                             int* __restrict__ rp,
                                             int2* __restrict__ edgesB) {
    __shared__ int lcnt[BROWS];
    __shared__ int lbase[BROWS];
    __shared__ int scan_tmp[256];
    int b = blockIdx.x, t = threadIdx.x;
    int s0 = brp[b], s1 = brp[b + 1];
    for (int i = t; i < BROWS; i += 256) lcnt[i] = 0;
    __syncthreads();
    for (int s = s0 + t; s < s1; s += 256)
        atomicAdd(&lcnt[edgesA[s].x >> 17], 1);
    __syncthreads();
    int a0 = lcnt[2 * t], a1 = lcnt[2 * t + 1];
    scan_tmp[t] = a0 + a1;
    __syncthreads();
    for (int off = 1; off < 256; off <<= 1) {
        int x = (t >= off) ? scan_tmp[t - off] : 0;
        __syncthreads();
        scan_tmp[t] += x;
        __syncthreads();
    }
    int tb = (t == 0) ? 0 : scan_tmp[t - 1];
    lbase[2 * t] = tb;
    lbase[2 * t + 1] = tb + a0;
    __syncthreads();
    int row0 = b * BROWS;
    for (int r = t; r < BROWS; r += 256) {
        int gr = row0 + r;
        if (gr < ROWS_TOTAL) rp[gr] = s0 + lbase[r];
    }
    for (int i = t; i < BROWS; i += 256) lcnt[i] = 0;  // reuse as cursors
    __syncthreads();
    for (int s = s0 + t; s < s1; s += 256) {
        int2 ent = edgesA[s];
        int rl = ent.x >> 17;
        int pos = s0 + lbase[rl] + atomicAdd(&lcnt[rl], 1);
        edgesB[pos] = ent;
    }
}

// unified full gather: each lane covers 2 features (ushort2); the wave's two
// 32-lane halves process 2 different edges concurrently -> 16 edges in flight
// per 8-deep unroll. Halves merged with one shfl_xor(32) pair at row end.
__global__ void spmm_gather(const unsigned short* __restrict__ ut,
                            const unsigned short* __restrict__ it,
                            const float* __restrict__ d_i, const float* __restrict__ d_j,
                            const int2* __restrict__ edges, const int* __restrict__ rp,
                            unsigned short* __restrict__ uo, unsigned short* __restrict__ io) {
    int r = blockIdx.x * (blockDim.x >> 6) + (threadIdx.x >> 6);
    if (r >= ROWS_TOTAL) return;
    int lane = threadIdx.x & 63;
    int half = lane >> 5;       // 0 or 1: which edge of the pair
    int sl = lane & 31;         // feature-pair index: features 2sl, 2sl+1
    bool isU = r < USER_NUM;
    const unsigned short* xsrc  = isU ? it : ut;
    const unsigned short* xself = isU ? ut : it;
    int selfrow = isU ? r : r - USER_NUM;
    float dsc = isU ? d_i[r] : d_j[r - USER_NUM];

    float accx = 0.f, accy = 0.f;
    if (half == 0) {
        unsigned s = *reinterpret_cast<const unsigned*>(
            xself + (size_t)selfrow * FDIM + 2 * sl);
        accx = dsc * bf2f_lo(s);
        accy = dsc * bf2f_hi(s);
    }
    int e = rp[r], e2 = rp[r + 1];

    // 8-deep, 2 edges per step = 16 edges in flight
    for (; e + 15 < e2; e += 16) {
        int2 ed[8];
        unsigned xv[8];
#pragma unroll
        for (int j = 0; j < 8; ++j) ed[j] = edges[e + 2 * j + half];
#pragma unroll
        for (int j = 0; j < 8; ++j)
            xv[j] = *reinterpret_cast<const unsigned*>(
                xsrc + (size_t)(ed[j].x & 0x1FFFF) * FDIM + 2 * sl);
#pragma unroll
        for (int j = 0; j < 8; ++j) {
            float v = __int_as_float(ed[j].y);
            accx = fmaf(v, bf2f_lo(xv[j]), accx);
            accy = fmaf(v, bf2f_hi(xv[j]), accy);
        }
    }
    // 4-deep, 2 edges per step
    for (; e + 7 < e2; e += 8) {
        int2 ed[4];
        unsigned xv[4];
#pragma unroll
        for (int j = 0; j < 4; ++j) ed[j] = edges[e + 2 * j + half];
#pragma unroll
        for (int j = 0; j < 4; ++j)
            xv[j] = *reinterpret_cast<const unsigned*>(
                xsrc + (size_t)(ed[j].x & 0x1FFFF) * FDIM + 2 * sl);
#pragma unroll
        for (int j = 0; j < 4; ++j) {
            float v = __int_as_float(ed[j].y);
            accx = fmaf(v, bf2f_lo(xv[j]), accx);
            accy = fmaf(v, bf2f_hi(xv[j]), accy);
        }
    }
    // pair tail
    for (; e + 1 < e2; e += 2) {
        int2 a = edges[e + half];
        unsigned x = *reinterpret_cast<const unsigned*>(
            xsrc + (size_t)(a.x & 0x1FFFF) * FDIM + 2 * sl);
        float v = __int_as_float(a.y);
        accx = fmaf(v, bf2f_lo(x), accx);
        accy = fmaf(v, bf2f_hi(x), accy);
    }
    // odd last edge: half 0 only
    if (e < e2 && half == 0) {
        int2 a = edges[e];
        unsigned x = *reinterpret_cast<const unsigned*>(
            xsrc + (size_t)(a.x & 0x1FFFF) * FDIM + 2 * sl);
        float v = __int_as_float(a.y);
        accx = fmaf(v, bf2f_lo(x), accx);
        accy = fmaf(v, bf2f_hi(x), accy);
    }

    // merge the two halves (feature sets are identical across halves)
    accx += __shfl_xor(accx, 32, 64);
    accy += __shfl_xor(accy, 32, 64);

    if (half == 0) {
        unsigned short* outp = isU ? uo : io;
        unsigned packed = (unsigned)f2bf(accx) | ((unsigned)f2bf(accy) << 16);
        *reinterpret_cast<unsigned*>(outp + (size_t)selfrow * FDIM + 2 * sl) = packed;
    }
}

// per-row partial layer-3 gather, 4-deep pipelined (head only, ~330K edges)
__device__ __forceinline__ float layer3_row(const unsigned short* __restrict__ src2,
                                            float dsc, float self2,
                                            const int2* __restrict__ edges,
                                            int e, int e2, int lane) {
    float acc = dsc * self2;
    for (; e + 3 < e2; e += 4) {
        int2 ed[4];
        float xv[4];
#pragma unroll
        for (int j = 0; j < 4; ++j) ed[j] = edges[e + j];
#pragma unroll
        for (int j = 0; j < 4; ++j)
            xv[j] = bf2f(src2[(size_t)(ed[j].x & 0x1FFFF) * FDIM + lane]);
#pragma unroll
        for (int j = 0; j < 4; ++j)
            acc = fmaf(__int_as_float(ed[j].y), xv[j], acc);
    }
    for (; e < e2; ++e) {
        int2 a = edges[e];
        acc = fmaf(__int_as_float(a.y), bf2f(src2[(size_t)(a.x & 0x1FFFF) * FDIM + lane]), acc);
    }
    return acc;
}

// fused head: computes layer-3 rows on the fly (only batch rows need them)
__global__ void batch_pred_fused(const unsigned short* __restrict__ u0,
                                 const unsigned short* __restrict__ u1,
                                 const unsigned short* __restrict__ u2,
                                 const unsigned short* __restrict__ i0,
                                 const unsigned short* __restrict__ i1,
                                 const unsigned short* __restrict__ i2,
                                 const float* __restrict__ d_i, const float* __restrict__ d_j,
                                 const int2* __restrict__ edges, const int* __restrict__ rp,
                                 const int* __restrict__ user, const int* __restrict__ item_i,
                                 const int* __restrict__ item_j,
                                 float* __restrict__ pred_i, float* __restrict__ pred_j,
                                 float* __restrict__ l2_terms, float* __restrict__ lsg_terms) {
    int b = blockIdx.x * (blockDim.x >> 6) + (threadIdx.x >> 6);
    if (b >= BATCH) return;
    int lane = threadIdx.x & 63;
    int uu = user[b], ii = item_i[b], ij = item_j[b];

    float ue0 = bf2f(u0[(size_t)uu * FDIM + lane]);
    float ue1 = bf2f(u1[(size_t)uu * FDIM + lane]);
    float ue2 = bf2f(u2[(size_t)uu * FDIM + lane]);
    float vi0 = bf2f(i0[(size_t)ii * FDIM + lane]);
    float vi1 = bf2f(i1[(size_t)ii * FDIM + lane]);
    float vi2 = bf2f(i2[(size_t)ii * FDIM + lane]);
    float vj0 = bf2f(i0[(size_t)ij * FDIM + lane]);
    float vj1 = bf2f(i1[(size_t)ij * FDIM + lane]);
    float vj2 = bf2f(i2[(size_t)ij * FDIM + lane]);

    float ue3 = layer3_row(i2, d_i[uu], ue2, edges, rp[uu], rp[uu + 1], lane);
    int ri = USER_NUM + ii, rj = USER_NUM + ij;
    float vi3 = layer3_row(u2, d_j[ii], vi2, edges, rp[ri], rp[ri + 1], lane);
    float vj3 = layer3_row(u2, d_j[ij], vj2, edges, rp[rj], rp[rj + 1], lane);

    float pi = ue0 * vi0 + ue1 * vi1 + ue2 * vi2 + ue3 * vi3;
    float pj = ue0 * vj0 + ue1 * vj1 + ue2 * vj2 + ue3 * vj3;
    float l2 = ue0 * ue0 + ue1 * ue1 + ue2 * ue2 + ue3 * ue3
             + vi0 * vi0 + vi1 * vi1 + vi2 * vi2 + vi3 * vi3
             + vj0 * vj0 + vj1 * vj1 + vj2 * vj2 + vj3 * vj3;
#pragma unroll
    for (int m = 32; m >= 1; m >>= 1) {
        pi += __shfl_xor(pi, m, 64);
        pj += __shfl_xor(pj, m, 64);
        l2 += __shfl_xor(l2, m, 64);
    }
    if (lane == 0) {
        pred_i[b] = pi;
        pred_j[b] = pj;
        l2_terms[b] = 0.01f * l2;
        float x = pi - pj;
        lsg_terms[b] = fminf(x, 0.f) - log1pf(expf(-fabsf(x)));
    }
}

__global__ void final_reduce(const float* __restrict__ l2_terms,
                             const float* __restrict__ lsg_terms,
                             float* __restrict__ out_loss, float* __restrict__ out_loss2) {
    __shared__ float s1[256];
    __shared__ float s2[256];
    int t = threadIdx.x;
    float a = 0.f, b = 0.f;
    for (int i = t; i < BATCH; i += 256) { a += l2_terms[i]; b += lsg_terms[i]; }
    s1[t] = a; s2[t] = b;
    __syncthreads();
    for (int s = 128; s >= 1; s >>= 1) {
        if (t < s) { s1[t] += s1[t + s]; s2[t] += s2[t + s]; }
        __syncthreads();
    }
    if (t == 0) {
        float loss2 = -s2[0] / (float)BATCH;
        *out_loss = loss2 + s1[0] / (float)BATCH;
        *out_loss2 = loss2;
    }
}

extern "C" void kernel_launch(void* const* d_in, const int* in_sizes, int n_in,
                              void* d_out, int out_size, void* d_ws, size_t ws_size,
                              hipStream_t stream) {
    const float* eu      = (const float*)d_in[0];
    const float* ei      = (const float*)d_in[1];
    const float* d_i     = (const float*)d_in[2];
    const float* d_j     = (const float*)d_in[3];
    const float* vals    = (const float*)d_in[4];
    const int*   e_users = (const int*)d_in[5];
    const int*   e_items = (const int*)d_in[6];
    const int*   user    = (const int*)d_in[7];
    const int*   item_i  = (const int*)d_in[8];
    const int*   item_j  = (const int*)d_in[9];

    float* ws = (float*)d_ws;
    size_t off = 0;
    const size_t UW = (size_t)USER_NUM * FDIM / 2;
    const size_t IW = (size_t)ITEM_NUM * FDIM / 2;
    unsigned short* ub[3];
    unsigned short* ib[3];
    for (int k = 0; k < 3; ++k) { ub[k] = (unsigned short*)(ws + off); off += UW; }
    for (int k = 0; k < 3; ++k) { ib[k] = (unsigned short*)(ws + off); off += IW; }
    float* l2t  = ws + off; off += BATCH;
    float* lsgt = ws + off; off += BATCH;
    int* bcnt       = (int*)(ws + off); off += 512;
    int* brp        = (int*)(ws + off); off += 512;
    int* bucket_cur = (int*)(ws + off); off += 512;
    int* rp         = (int*)(ws + off); off += ROWS_TOTAL + 16;
    int2* edgesA = (int2*)(ws + off); off += (size_t)4 * N_EDGES;
    int2* edgesB = (int2*)(ws + off); off += (size_t)4 * N_EDGES;

    float* outp   = (float*)d_out;
    float* pred_i = outp;
    float* pred_j = outp + BATCH;
    float* loss   = outp + 2 * BATCH;
    float* loss2  = loss + 1;

    dim3 blk(256);

    int nU4 = USER_NUM * FDIM / 4, nI4 = ITEM_NUM * FDIM / 4;
    f32_to_bf16_k<<<(nU4 + 255) / 256, blk, 0, stream>>>(eu, ub[0], nU4);
    f32_to_bf16_k<<<(nI4 + 255) / 256, blk, 0, stream>>>(ei, ib[0], nI4);

    zero_ints<<<1, 512, 0, stream>>>(bcnt, NB);
    bucket_hist<<<768, blk, 0, stream>>>(e_users, e_items, bcnt, N_EDGES);
    bucket_scan<<<1, 512, 0, stream>>>(bcnt, brp, bucket_cur, rp);
    passA<<<(N_EDGES + CHUNK_E - 1) / CHUNK_E, blk, 0, stream>>>(
        e_users, e_items, vals, bucket_cur, edgesA, N_EDGES);
    passB<<<NB, blk, 0, stream>>>(edgesA, brp, rp, edgesB);

    // layers 1 and 2, full gathers
    int gridG = (ROWS_TOTAL + 3) / 4;
    for (int k = 0; k < 2; ++k) {
        spmm_gather<<<gridG, blk, 0, stream>>>(ub[k], ib[k], d_i, d_j,
                                               edgesB, rp, ub[k + 1], ib[k + 1]);
    }

    // layer 3 computed only for batch rows, fused into the head
    batch_pred_fused<<<(BATCH + 3) / 4, blk, 0, stream>>>(
        ub[0], ub[1], ub[2], ib[0], ib[1], ib[2],
        d_i, d_j, edgesB, rp, user, item_i, item_j,
        pred_i, pred_j, l2t, lsgt);
    final_reduce<<<1, 256, 0, stream>>>(l2t, lsgt, loss, loss2);
}